// Round 8
// baseline (699.038 us; speedup 1.0000x reference)
//
#include <hip/hip_runtime.h>
#include <hip/hip_bf16.h>

// Shapes
#define BB   64
#define NN   512
#define EE   2048
#define FINK 300
#define DD   256
#define BN_TOT (BB*NN)    // 32768
#define BE_TOT (BB*EE)    // 131072
#define EPSF 1e-5f

using bf16 = __hip_bfloat16;
typedef unsigned short u16;
typedef __attribute__((ext_vector_type(8))) short short8;
typedef __attribute__((ext_vector_type(4))) float f32x4;
typedef __attribute__((ext_vector_type(4))) unsigned short u16x4;

__device__ __forceinline__ float tf(float x) { return x; }
__device__ __forceinline__ float tf(bf16 x)  { return __bfloat162float(x); }
__device__ __forceinline__ void  stv(float* p, float v) { *p = v; }
__device__ __forceinline__ void  stv(bf16*  p, float v) { *p = __float2bfloat16(v); }

__device__ __forceinline__ u16 f2bu(float f) {
    bf16 b = __float2bfloat16(f);
    return *(u16*)&b;
}
// f32x4 -> 4x bf16 stored as one 8B write
__device__ __forceinline__ void st4b(u16* p, f32x4 v)
{
    u16x4 o;
    o[0] = f2bu(v[0]); o[1] = f2bu(v[1]); o[2] = f2bu(v[2]); o[3] = f2bu(v[3]);
    *(u16x4*)p = o;
}

// Direct global->LDS DMA, 16B per lane. LDS dst = wave-uniform base + lane*16.
__device__ __forceinline__ void gload16(const void* g, void* l)
{
    __builtin_amdgcn_global_load_lds((const __attribute__((address_space(1))) void*)g,
                                     (__attribute__((address_space(3))) void*)l, 16, 0, 0);
}

// Int dtype probe: lengths[1] as int32 is in [256,512] iff int32 storage;
// it is the zero hi-word of lengths[0] iff int64 (LE).
__global__ void detect_kernel(const int* __restrict__ lengths, int* __restrict__ flags)
{
    flags[1] = (lengths[1] == 0) ? 1 : 0;
}

__global__ void conv_i(const void* __restrict__ src, int* __restrict__ dst, int n,
                       const int* __restrict__ flags)
{
    int i = blockIdx.x * 256 + threadIdx.x;
    if (i >= n) return;
    const int* s = (const int*)src;
    dst[i] = s[flags[1] ? (i << 1) : i];
}

// f32 -> bf16 flat, 4 elems/thread (n % 4 == 0)
__global__ void conv_f2b(const float* __restrict__ src, u16* __restrict__ dst, int n4)
{
    int i = blockIdx.x * 256 + threadIdx.x;
    if (i >= n4) return;
    f32x4 v = *(const f32x4*)&src[i * 4];
    st4b(&dst[i * 4], v);
}

// f32 (rows x sk) -> bf16 (rows x dk) zero-padded, 4 cols/thread.
// Requires sk%4==0, dk%4==0, sk*4B row stride 16B-aligned (sk%4==0 ensures).
__global__ void conv_pad(const float* __restrict__ src, u16* __restrict__ dst, int rows,
                         int sk, int dk)
{
    int dk4 = dk >> 2;
    int i = blockIdx.x * 256 + threadIdx.x;
    if (i >= rows * dk4) return;
    int r = i / dk4, c4 = (i - r * dk4) * 4;
    if (c4 < sk) {
        f32x4 v = *(const f32x4*)&src[(size_t)r * sk + c4];
        st4b(&dst[(size_t)r * dk + c4], v);
    } else {
        *(u16x4*)&dst[(size_t)r * dk + c4] = (u16x4){0, 0, 0, 0};
    }
}

// W3[:, :256] (stride 512) -> bf16 256x256, 4 cols/thread (16384 threads)
__global__ void conv_w3a(const float* __restrict__ W3, u16* __restrict__ dst)
{
    int i = blockIdx.x * 256 + threadIdx.x;
    int r = i >> 6, c4 = (i & 63) * 4;
    f32x4 v = *(const f32x4*)&W3[r * 512 + c4];
    st4b(&dst[r * 256 + c4], v);
}

// ---------------------------------------------------------------------------
// m97-style MFMA GEMM: C[m,n] = sum_k A[m,k]*W[n*ldw+k] (+bias,+relu)
// A, W bf16 (u16) row-major; tile 128x128, 4 waves, K-step 32.
// Staging via global_load_lds width=16 into unpadded [128][32] LDS tiles
// (DMA writes lane i at base + i*16B -> rows packed 4 lanes/row).
// M,N multiples of 128; K multiple of 32; lda/ldw elems, rows 16B-aligned.
// ---------------------------------------------------------------------------
template<typename TC, int RELU>
__global__ __launch_bounds__(256)
void gemm_bf(const u16* __restrict__ A, const u16* __restrict__ W,
             const float* __restrict__ bias, TC* __restrict__ C,
             int M, int N, int K, int lda, int ldw)
{
    __shared__ u16 As[128 * 32];
    __shared__ u16 Ws[128 * 32];

    const int m0 = blockIdx.y * 128;
    const int n0 = blockIdx.x * 128;
    const int tid  = threadIdx.x;
    const int lane = tid & 63;
    const int wv   = tid >> 6;
    const int fr   = lane & 15;
    const int q8   = (lane >> 4) * 8;
    const int mb   = (wv >> 1) * 64;
    const int nb   = (wv & 1) * 64;

    const int r16 = lane >> 2;          // 0..15 (staging row within 16-row group)
    const int c8  = (lane & 3) * 8;     // 0,8,16,24 (k sub-offset)

    f32x4 acc[4][4];
#pragma unroll
    for (int i = 0; i < 4; i++)
#pragma unroll
        for (int j = 0; j < 4; j++) acc[i][j] = (f32x4){0.f, 0.f, 0.f, 0.f};

    for (int k0 = 0; k0 < K; k0 += 32) {
        __syncthreads();
#pragma unroll
        for (int j = 0; j < 2; j++) {
            int rowA = m0 + wv * 32 + j * 16 + r16;
            int rowW = n0 + wv * 32 + j * 16 + r16;
            gload16(A + (size_t)rowA * lda + k0 + c8, &As[(wv * 32 + j * 16) * 32]);
            gload16(W + (size_t)rowW * ldw + k0 + c8, &Ws[(wv * 32 + j * 16) * 32]);
        }
        __syncthreads();

        short8 af[4], bf[4];
#pragma unroll
        for (int i = 0; i < 4; i++) af[i] = *(const short8*)&As[(mb + i * 16 + fr) * 32 + q8];
#pragma unroll
        for (int j = 0; j < 4; j++) bf[j] = *(const short8*)&Ws[(nb + j * 16 + fr) * 32 + q8];
#pragma unroll
        for (int i = 0; i < 4; i++)
#pragma unroll
            for (int j = 0; j < 4; j++)
                acc[i][j] = __builtin_amdgcn_mfma_f32_16x16x32_bf16(af[i], bf[j], acc[i][j], 0, 0, 0);
    }

#pragma unroll
    for (int i = 0; i < 4; i++) {
#pragma unroll
        for (int j = 0; j < 4; j++) {
            int gn = n0 + nb + j * 16 + fr;
            float bv = bias ? bias[gn] : 0.f;
#pragma unroll
            for (int r = 0; r < 4; r++) {
                int gm = m0 + mb + i * 16 + (lane >> 4) * 4 + r;
                float v = acc[i][j][r] + bv;
                if (RELU) v = fmaxf(v, 0.f);
                stv(&C[(size_t)gm * N + gn], v);
            }
        }
    }
}

// M = W3b @ W2 (256 x 64) f32+bf16; sb[d] = row-sum of W3b.
__global__ void prep_M(const float* __restrict__ W3, const float* __restrict__ W2,
                       u16* __restrict__ Mb, float* __restrict__ sb)
{
    int d = blockIdx.x, a = threadIdx.x;
    float s = 0.f;
    for (int j = 0; j < 256; j++)
        s += W3[d * 512 + 256 + j] * W2[j * 64 + a];
    Mb[d * 64 + a] = f2bu(s);
    if (a == 0) {
        float t = 0.f;
        for (int j = 0; j < 256; j++) t += W3[d * 512 + 256 + j];
        sb[d] = t;
    }
}

// ---------------------------------------------------------------------------
// Per-batch counting sort of edges by column. One block per batch, 512 thr.
// v2: emits flattened per-slot records edat = {(e<<16)|row, norm} so the
// gather kernel has NO pointer chase (norm computed here from LDS counts).
// ---------------------------------------------------------------------------
__global__ __launch_bounds__(512)
void sort_edges(const int* __restrict__ ecol, const int* __restrict__ erow,
                float* __restrict__ deg, int* __restrict__ node_off,
                uint2* __restrict__ edat)
{
    const int b = blockIdx.x;
    const int t = threadIdx.x;
    const int base = b * EE;
    __shared__ int cnt[512];
    __shared__ int tmp[512];
    __shared__ int off2[512];

    cnt[t] = 0;
    __syncthreads();
    for (int e = t; e < EE; e += 512) atomicAdd(&cnt[ecol[base + e]], 1);
    __syncthreads();

    int v = cnt[t];
    deg[b * NN + t] = (float)(v + 1);
    tmp[t] = v;
    __syncthreads();
    for (int s = 1; s < 512; s <<= 1) {
        int y = (t >= s) ? tmp[t - s] : 0;
        __syncthreads();
        tmp[t] += y;
        __syncthreads();
    }
    int excl = tmp[t] - v;
    node_off[b * NN + t] = excl;
    off2[t] = excl;
    __syncthreads();
    for (int e = t; e < EE; e += 512) {
        int c = ecol[base + e];
        int r = erow[base + e];
        int pos = atomicAdd(&off2[c], 1);
        float nrm = rsqrtf((float)((cnt[r] + 1) * (cnt[c] + 1)));
        edat[base + pos] = make_uint2(((unsigned)e << 16) | (unsigned)r,
                                      __float_as_uint(nrm));
    }
}

// ---------------------------------------------------------------------------
// Gather aggregation v2 (no atomics, no pointer chase): one block per node.
// Wave w handles edges start+w, start+w+4, ... ; y1 row read as float4
// (64 lanes x 16B = full 256-dim row per wave); eattr's 64 dims map onto the
// wave's 64 lanes. Cross-wave LDS reduce at the end.
// ---------------------------------------------------------------------------
__global__ __launch_bounds__(256)
void edge_gather(const uint2* __restrict__ edat, const int* __restrict__ node_off,
                 const float* __restrict__ y1, const float* __restrict__ eattr,
                 float* __restrict__ agg1, u16* __restrict__ eaggb)
{
    const int j = blockIdx.x;
    const int b = j >> 9;
    const int cc = j & 511;
    const int tid  = threadIdx.x;
    const int wv   = tid >> 6;
    const int lane = tid & 63;
    const int start = node_off[j];
    const int end   = (cc == 511) ? EE : node_off[j + 1];

    f32x4 acc = (f32x4){0.f, 0.f, 0.f, 0.f};
    float acce = 0.f;
    for (int i = start + wv; i < end; i += 4) {
        uint2 ed = edat[(size_t)b * EE + i];
        float nw = __uint_as_float(ed.y);
        int r = (int)(ed.x & 0xffffu);
        int e = (int)(ed.x >> 16);
        f32x4 yv = *(const f32x4*)&y1[((size_t)(b * NN + r)) * 256 + lane * 4];
        acc += nw * yv;
        acce += nw * eattr[((size_t)(b * EE + e)) * 64 + lane];
    }

    __shared__ f32x4 redA[4][64];
    __shared__ float redB[4][64];
    redA[wv][lane] = acc;
    redB[wv][lane] = acce;
    __syncthreads();
    if (tid < 64) {
        f32x4 s = redA[0][tid];
        float se = redB[0][tid];
#pragma unroll
        for (int w = 1; w < 4; w++) { s += redA[w][tid]; se += redB[w][tid]; }
        *(f32x4*)&agg1[(size_t)j * 256 + tid * 4] = s;
        eaggb[(size_t)j * 64 + tid] = f2bu(se);
    }
}

// h = tanh((agg1 + aggM + (y1+sb)/deg)/deg + bias) * mask -> aggM in place
// v2: f32x4, 4 elems/thread; grid BN_TOT/4 blocks of 256.
__global__ void gcn_finalize(const float* __restrict__ agg1, float* __restrict__ aggM,
                             const float* __restrict__ y1, const float* __restrict__ sb,
                             const float* __restrict__ deg, const float* __restrict__ gcn_bias,
                             const int* __restrict__ lengths)
{
    int idx4 = blockIdx.x * 256 + threadIdx.x;       // group-of-4 index
    int j  = idx4 >> 6;
    int d4 = (idx4 & 63) * 4;
    size_t base = (size_t)j * 256 + d4;
    float dg = deg[j];
    float inv = 1.f / dg;
    f32x4 a1 = *(const f32x4*)&agg1[base];
    f32x4 aM = *(const f32x4*)&aggM[base];
    f32x4 yv = *(const f32x4*)&y1[base];
    f32x4 sv = *(const f32x4*)&sb[d4];
    f32x4 gb = *(const f32x4*)&gcn_bias[d4];
    int b = j >> 9, p = j & 511;
    bool live = (p < lengths[b]);
    f32x4 o;
#pragma unroll
    for (int k = 0; k < 4; k++) {
        float a = (a1[k] + aM[k] + (yv[k] + sv[k]) * inv) * inv;
        o[k] = live ? tanhf(a + gb[k]) : 0.f;
    }
    *(f32x4*)&aggM[base] = o;
}

// v2: wave reads full 256-col rows as f32x4; LDS cross-wave combine; 256
// atomics per block. Grid 512 x 256.
__global__ void bn_stats(const float* __restrict__ X, float* __restrict__ sums,
                         float* __restrict__ sumsq, int R)
{
    int wv = threadIdx.x >> 6, lane = threadIdx.x & 63;
    f32x4 s = (f32x4){0.f, 0.f, 0.f, 0.f};
    f32x4 q = (f32x4){0.f, 0.f, 0.f, 0.f};
    for (int r = blockIdx.x * 4 + wv; r < R; r += gridDim.x * 4) {
        f32x4 v = *(const f32x4*)&X[(size_t)r * DD + lane * 4];
        s += v; q += v * v;
    }
    __shared__ f32x4 rs[4][64], rq[4][64];
    rs[wv][lane] = s; rq[wv][lane] = q;
    __syncthreads();
    if (threadIdx.x < 64) {
        f32x4 ts = rs[0][lane], tq = rq[0][lane];
#pragma unroll
        for (int w = 1; w < 4; w++) { ts += rs[w][lane]; tq += rq[w][lane]; }
#pragma unroll
        for (int k = 0; k < 4; k++) {
            atomicAdd(&sums[lane * 4 + k], ts[k]);
            atomicAdd(&sumsq[lane * 4 + k], tq[k]);
        }
    }
}

// X normalized in place; optional bf16 duplicate. v2: f32x4 / 4 per thread.
__global__ void bn_apply(float* __restrict__ X, const float* __restrict__ sums,
                         const float* __restrict__ sumsq, const float* __restrict__ g,
                         const float* __restrict__ bt, int R, u16* __restrict__ dup)
{
    int idx4 = blockIdx.x * 256 + threadIdx.x;
    int d4 = (idx4 & 63) * 4;
    size_t base = (size_t)idx4 * 4;
    float invR = 1.f / (float)R;
    f32x4 sm = *(const f32x4*)&sums[d4];
    f32x4 sq = *(const f32x4*)&sumsq[d4];
    f32x4 gv = *(const f32x4*)&g[d4];
    f32x4 bv = *(const f32x4*)&bt[d4];
    f32x4 x  = *(const f32x4*)&X[base];
    f32x4 o;
#pragma unroll
    for (int k = 0; k < 4; k++) {
        float m   = sm[k] * invR;
        float var = sq[k] * invR - m * m;
        o[k] = (x[k] - m) * rsqrtf(fmaxf(var, 0.f) + EPSF) * gv[k] + bv[k];
    }
    *(f32x4*)&X[base] = o;
    if (dup) st4b(&dup[base], o);
}

// ---------------------------------------------------------------------------
// MFMA flash attention. v5b: 512-thread blocks, 8 waves, 128 q-rows per
// block; grid = BB*4*4 = 1024 blocks; qp = bid>>8 keeps the 4 q-quarters of
// a (b,h) on one XCD. __launch_bounds__(512,2) = 128-VGPR budget (no spill).
// exp2-folded softmax; Ps stride 138; XOR-swizzled V^T.
// ---------------------------------------------------------------------------
__global__ __launch_bounds__(512, 2)
void attn_mfma(const bf16* __restrict__ qkv, u16* __restrict__ out)
{
    const int bid = blockIdx.x;
    const int qp = bid >> 8;        // 0..3 (slow bits -> XCD-coherent (b,h))
    const int pr = bid & 255;
    const int h  = pr & 3;
    const int b  = pr >> 2;

    const int tid  = threadIdx.x;
    const int lane = tid & 63;
    const int wv   = tid >> 6;      // 0..7
    const int fr   = lane & 15;
    const int quad = lane >> 4;
    const int q8   = quad * 8;

    __shared__ u16 Ks[128][72];
    __shared__ u16 Vts[64][136];
    __shared__ u16 Ps[128][138];

    const u16* qb = (const u16*)qkv;
    const size_t bb = (size_t)(b * NN);
    const float CE = 0.125f * 1.44269504f;   // softmax scale folded into exp2

    // Q fragments in registers: wave wv owns q-rows qp*128 + wv*16 + fr.
    short8 aq[2];
#pragma unroll
    for (int ks = 0; ks < 2; ks++)
        aq[ks] = *(const short8*)(qb + (bb + qp * 128 + wv * 16 + fr) * 768
                                  + h * 64 + ks * 32 + q8);

    f32x4 O[4];
    float m_i[4], l_i[4];
#pragma unroll
    for (int t = 0; t < 4; t++) {
        O[t] = (f32x4){0.f, 0.f, 0.f, 0.f};
        m_i[t] = -1e30f; l_i[t] = 0.f;
    }

    for (int c = 0; c < 4; c++) {
        __syncthreads();            // previous chunk's LDS reads complete
#pragma unroll
        for (int i = 0; i < 2; i++) {
            int idx = i * 512 + tid;
            int r = idx >> 3, seg = idx & 7;
            uint4 u = *((const uint4*)(qb + (bb + c * 128 + r) * 768 + 256 + h * 64) + seg);
            *(uint4*)&Ks[r][seg * 8] = u;
            uint4 v = *((const uint4*)(qb + (bb + c * 128 + r) * 768 + 512 + h * 64) + seg);
            // V^T store, 16B-granular XOR swizzle (seg == d>>3 for all 8 elems)
            u16* dst = &Vts[seg * 8][r ^ (seg << 3)];
            dst[0*136] = (u16)(v.x & 0xffff); dst[1*136] = (u16)(v.x >> 16);
            dst[2*136] = (u16)(v.y & 0xffff); dst[3*136] = (u16)(v.y >> 16);
            dst[4*136] = (u16)(v.z & 0xffff); dst[5*136] = (u16)(v.z >> 16);
            dst[6*136] = (u16)(v.w & 0xffff); dst[7*136] = (u16)(v.w >> 16);
        }
        __syncthreads();

        f32x4 S[8];
#pragma unroll
        for (int t = 0; t < 8; t++) S[t] = (f32x4){0.f, 0.f, 0.f, 0.f};
        __builtin_amdgcn_s_setprio(1);
#pragma unroll
        for (int ks = 0; ks < 2; ks++) {
#pragma unroll
            for (int t = 0; t < 8; t++) {
                short8 bk = *(const short8*)&Ks[t * 16 + fr][ks * 32 + q8];
                S[t] = __builtin_amdgcn_mfma_f32_16x16x32_bf16(aq[ks], bk, S[t], 0, 0, 0);
            }
        }
        __builtin_amdgcn_s_setprio(0);

        float mc[4];
#pragma unroll
        for (int r = 0; r < 4; r++) {
            float mm = -1e30f;
#pragma unroll
            for (int t = 0; t < 8; t++) mm = fmaxf(mm, S[t][r]);
            mc[r] = mm;
        }
#pragma unroll
        for (int msk = 1; msk < 16; msk <<= 1)
#pragma unroll
            for (int r = 0; r < 4; r++) mc[r] = fmaxf(mc[r], __shfl_xor(mc[r], msk));

        float alpha[4], ls[4];
#pragma unroll
        for (int r = 0; r < 4; r++) {
            float mn = fmaxf(m_i[r], mc[r]);
            alpha[r] = __builtin_amdgcn_exp2f((m_i[r] - mn) * CE);
            m_i[r] = mn;
            ls[r] = 0.f;
        }
#pragma unroll
        for (int t = 0; t < 8; t++)
#pragma unroll
            for (int r = 0; r < 4; r++) {
                float p = __builtin_amdgcn_exp2f((S[t][r] - m_i[r]) * CE);
                Ps[wv * 16 + quad * 4 + r][t * 16 + fr] = f2bu(p);
                ls[r] += p;
            }
#pragma unroll
        for (int msk = 1; msk < 16; msk <<= 1)
#pragma unroll
            for (int r = 0; r < 4; r++) ls[r] += __shfl_xor(ls[r], msk);
#pragma unroll
        for (int r = 0; r < 4; r++) l_i[r] = l_i[r] * alpha[r] + ls[r];
#pragma unroll
        for (int t = 0; t < 4; t++)
#pragma unroll
            for (int r = 0; r < 4; r++) O[t][r] *= alpha[r];

        __builtin_amdgcn_s_setprio(1);
#pragma unroll
        for (int ks = 0; ks < 4; ks++) {
            short8 ap = *(const short8*)&Ps[wv * 16 + fr][ks * 32 + q8];
#pragma unroll
            for (int t = 0; t < 4; t++) {
                short8 bv = *(const short8*)&Vts[t * 16 + fr]
                                [(ks * 32 + q8) ^ ((t * 2 + (fr >> 3)) << 3)];
                O[t] = __builtin_amdgcn_mfma_f32_16x16x32_bf16(ap, bv, O[t], 0, 0, 0);
            }
        }
        __builtin_amdgcn_s_setprio(0);
    }

#pragma unroll
    for (int t = 0; t < 4; t++)
#pragma unroll
        for (int r = 0; r < 4; r++) {
            int q = qp * 128 + wv * 16 + quad * 4 + r;
            out[(bb + q) * 256 + h * 64 + t * 16 + fr] = f2bu(O[t][r] / l_i[r]);
        }
}

// out = LN(X + Y); optional bf16 duplicate.
// v2: one WAVE per row (4 rows per 256-thr block, grid BN_TOT/4), f32x4
// loads, shfl_xor reductions — zero barriers (replaces 16-barrier tree).
__global__ void add_ln_kernel(const float* __restrict__ X, const float* __restrict__ Y,
                              const float* __restrict__ g, const float* __restrict__ bt,
                              float* __restrict__ out, u16* __restrict__ dup)
{
    int wv = threadIdx.x >> 6, lane = threadIdx.x & 63;
    int row = blockIdx.x * 4 + wv;
    size_t base = (size_t)row * DD + lane * 4;
    f32x4 v = *(const f32x4*)&X[base] + *(const f32x4*)&Y[base];
    float s = v[0] + v[1] + v[2] + v[3];
#pragma unroll
    for (int m = 1; m < 64; m <<= 1) s += __shfl_xor(s, m);
    float mean = s * (1.f / DD);
    f32x4 d;
#pragma unroll
    for (int k = 0; k < 4; k++) d[k] = v[k] - mean;
    float q = d[0]*d[0] + d[1]*d[1] + d[2]*d[2] + d[3]*d[3];
#pragma unroll
    for (int m = 1; m < 64; m <<= 1) q += __shfl_xor(q, m);
    float inv = rsqrtf(q * (1.f / DD) + EPSF);
    f32x4 gv = *(const f32x4*)&g[lane * 4];
    f32x4 bv = *(const f32x4*)&bt[lane * 4];
    f32x4 o;
#pragma unroll
    for (int k = 0; k < 4; k++) o[k] = d[k] * inv * gv[k] + bv[k];
    *(f32x4*)&out[base] = o;
    if (dup) st4b(&dup[base], o);
}

// v2: wave w handles rows w, w+4, ...; f32x4 over 4 cols/lane; LDS combine.
__global__ void pool_kernel(const float* __restrict__ enc, const int* __restrict__ lengths,
                            float* __restrict__ poolbuf)
{
    int b = blockIdx.x;
    int wv = threadIdx.x >> 6, lane = threadIdx.x & 63;
    int L = lengths[b];
    if (L < 1) L = 1;
    f32x4 s  = (f32x4){0.f, 0.f, 0.f, 0.f};
    f32x4 mx = (f32x4){-1e30f, -1e30f, -1e30f, -1e30f};
    for (int n = wv; n < NN; n += 4) {
        f32x4 v = *(const f32x4*)&enc[((size_t)b * NN + n) * DD + lane * 4];
        s += v;
        if (n < L) {
#pragma unroll
            for (int k = 0; k < 4; k++) mx[k] = fmaxf(mx[k], v[k]);
        }
    }
    __shared__ f32x4 rs[4][64], rm[4][64];
    rs[wv][lane] = s; rm[wv][lane] = mx;
    __syncthreads();
    if (threadIdx.x < 64) {
        f32x4 ts = rs[0][lane], tm = rm[0][lane];
#pragma unroll
        for (int w = 1; w < 4; w++) {
            ts += rs[w][lane];
#pragma unroll
            for (int k = 0; k < 4; k++) tm[k] = fmaxf(tm[k], rm[w][lane][k]);
        }
        float invL = 1.f / (float)L;
#pragma unroll
        for (int k = 0; k < 4; k++) {
            poolbuf[b * 512 + lane * 4 + k]       = tm[k];
            poolbuf[b * 512 + 256 + lane * 4 + k] = ts[k] * invL;
        }
    }
}

__global__ void head_kernel(const float* __restrict__ poolbuf, const float* __restrict__ lin_w,
                            const float* __restrict__ lin_b, const float* __restrict__ g,
                            const float* __restrict__ bt, float* __restrict__ out)
{
    int b = threadIdx.x;
    float r0 = lin_b[0], r1 = lin_b[1];
    for (int k = 0; k < 512; k++) {
        float p = poolbuf[b * 512 + k];
        r0 += p * lin_w[k];
        r1 += p * lin_w[512 + k];
    }
    __shared__ float s0[64], s1[64], mstat[4];
    s0[b] = r0; s1[b] = r1; __syncthreads();
    if (b == 0) {
        float a0 = 0, a1 = 0, q0 = 0, q1 = 0;
        for (int i = 0; i < 64; i++) { a0 += s0[i]; a1 += s1[i]; }
        a0 *= (1.f / 64.f); a1 *= (1.f / 64.f);
        for (int i = 0; i < 64; i++) {
            float d0 = s0[i] - a0, d1 = s1[i] - a1;
            q0 += d0 * d0; q1 += d1 * d1;
        }
        mstat[0] = a0; mstat[1] = a1; mstat[2] = q0 * (1.f / 64.f); mstat[3] = q1 * (1.f / 64.f);
    }
    __syncthreads();
    float z0 = (r0 - mstat[0]) * rsqrtf(mstat[2] + EPSF) * g[0] + bt[0];
    float z1 = (r1 - mstat[1]) * rsqrtf(mstat[3] + EPSF) * g[1] + bt[1];
    float mx = fmaxf(z0, z1);
    float e0 = __expf(z0 - mx), e1 = __expf(z1 - mx);
    float inv = 1.f / (e0 + e1);
    out[b * 2 + 0] = e0 * inv;
    out[b * 2 + 1] = e1 * inv;
}

extern "C" void kernel_launch(void* const* d_in, const int* in_sizes, int n_in,
                              void* d_out, int out_size, void* d_ws, size_t ws_size,
                              hipStream_t stream)
{
    (void)in_sizes; (void)n_in; (void)out_size; (void)ws_size;
    const float* x          = (const float*)d_in[0];
    const float* edge_attr  = (const float*)d_in[1];
    const float* W1         = (const float*)d_in[5];
    const float* W2         = (const float*)d_in[6];
    const float* W3         = (const float*)d_in[7];
    const float* b3         = (const float*)d_in[8];
    const float* gcn_bias   = (const float*)d_in[9];
    const float* bn1_g      = (const float*)d_in[10];
    const float* bn1_b      = (const float*)d_in[11];
    const float* in_proj_w  = (const float*)d_in[12];
    const float* in_proj_b  = (const float*)d_in[13];
    const float* out_proj_w = (const float*)d_in[14];
    const float* out_proj_b = (const float*)d_in[15];
    const float* ln1_g      = (const float*)d_in[16];
    const float* ln1_b      = (const float*)d_in[17];
    const float* lin1_w     = (const float*)d_in[18];
    const float* lin1_b     = (const float*)d_in[19];
    const float* lin2_w     = (const float*)d_in[20];
    const float* lin2_b     = (const float*)d_in[21];
    const float* ln2_g      = (const float*)d_in[22];
    const float* ln2_b      = (const float*)d_in[23];
    const float* bn2_g      = (const float*)d_in[24];
    const float* bn2_b      = (const float*)d_in[25];
    const float* lin_w      = (const float*)d_in[26];
    const float* lin_b      = (const float*)d_in[27];
    const float* bn3_g      = (const float*)d_in[28];
    const float* bn3_b      = (const float*)d_in[29];

    // ---- Workspace layout (~186 MB) ----
    char* p = (char*)d_ws;
    u16*   big   = (u16*)p;   p += (size_t)BN_TOT * 1024 * 2;   // 64 MiB: [xb|xsb|eaggb] -> qkv -> ffa
    float* bufA  = (float*)p; p += (size_t)BN_TOT * 256 * 4;    // aggM/h -> ffb
    float* bufB  = (float*)p; p += (size_t)BN_TOT * 256 * 4;    // y1 -> attnp -> h2
    float* bufC  = (float*)p; p += (size_t)BN_TOT * 256 * 4;    // agg1 -> h1
    u16*   bufP  = (u16*)p;   p += (size_t)BN_TOT * 256 * 2;    // 16.8 MB: hb -> attnoutb -> h1b
    float* deg   = (float*)p; p += (size_t)BN_TOT * 4;
    u16*   Mb    = (u16*)p;   p += 256 * 64 * 2;
    float* sb    = (float*)p; p += 1024;
    float* stats = (float*)p; p += 4 * 256 * 4;
    float* poolbuf=(float*)p; p += 64 * 512 * 4;
    int*   flags = (int*)p;   p += 256;
    int*   erc   = (int*)p;   p += BE_TOT * 4;
    int*   ecc   = (int*)p;   p += BE_TOT * 4;
    int*   lenc  = (int*)p;   p += 256;
    uint2* edat  = (uint2*)p; p += (size_t)BE_TOT * 8;
    int*   noff  = (int*)p;   p += BN_TOT * 4;
    u16*   W1b   = (u16*)p;   p += 256 * 320 * 2;
    u16*   W3ab  = (u16*)p;   p += 256 * 256 * 2;
    u16*   ipwb  = (u16*)p;   p += 768 * 256 * 2;
    u16*   opwb  = (u16*)p;   p += 256 * 256 * 2;
    u16*   l1wb  = (u16*)p;   p += 1024 * 256 * 2;
    u16*   l2wb  = (u16*)p;   p += 256 * 1024 * 2;

    // bf16 temporaries inside big (all dead before qkv is written at in_proj)
    u16* xb    = big;                              // 32768 x 320
    u16* xsb   = big + (size_t)BN_TOT * 320;       // 32768 x 256
    u16* eaggb = big + (size_t)BN_TOT * (320+256); // 32768 x 64
    bf16* qkv  = (bf16*)big;
    bf16* ffa  = (bf16*)big;

    float* y1      = bufB;
    float* agg1    = bufC;
    float* aggM    = bufA;    // becomes h in finalize
    float* h       = bufA;
    u16*   hb      = bufP;
    u16*   attnoutb= bufP;    // hb dead after in_proj GEMM
    float* attnp   = bufB;    // y1 dead after finalize
    float* h1      = bufC;    // agg1 dead after finalize
    u16*   h1b     = bufP;    // attnoutb dead after out_proj GEMM
    float* ffb     = bufA;    // h dead after add_ln #1
    float* h2      = bufB;    // attnp dead after add_ln #1

    hipMemsetAsync(stats, 0, 4 * 256 * 4, stream);

    detect_kernel<<<1, 1, 0, stream>>>((const int*)d_in[4], flags);
    conv_i<<<(BE_TOT + 255) / 256, 256, 0, stream>>>(d_in[2], erc, BE_TOT, flags);
    conv_i<<<(BE_TOT + 255) / 256, 256, 0, stream>>>(d_in[3], ecc, BE_TOT, flags);
    conv_i<<<1, 64, 0, stream>>>(d_in[4], lenc, BB, flags);

    // weight / input bf16 conversions — all vectorized 4 elems/thread
    conv_pad<<<(BN_TOT * 80 + 255) / 256, 256, 0, stream>>>(x, xb, BN_TOT, FINK, 320);
    conv_pad<<<(256 * 80 + 255) / 256, 256, 0, stream>>>(W1, W1b, 256, FINK, 320);
    conv_w3a<<<64, 256, 0, stream>>>(W3, W3ab);
    conv_f2b<<<(768 * 64 + 255) / 256, 256, 0, stream>>>(in_proj_w, ipwb, 768 * 64);
    conv_f2b<<<(256 * 64 + 255) / 256, 256, 0, stream>>>(out_proj_w, opwb, 256 * 64);
    conv_f2b<<<(1024 * 64 + 255) / 256, 256, 0, stream>>>(lin1_w, l1wb, 1024 * 64);
    conv_f2b<<<(256 * 256 + 255) / 256, 256, 0, stream>>>(lin2_w, l2wb, 256 * 256);

    prep_M<<<256, 64, 0, stream>>>(W3, W2, Mb, sb);
    sort_edges<<<BB, 512, 0, stream>>>(ecc, erc, deg, noff, edat);

    // xs = x @ W1.T  (bf16 out, K padded to 320)
    gemm_bf<bf16, 0><<<dim3(2, 256), 256, 0, stream>>>(
        xb, W1b, nullptr, (bf16*)xsb, BN_TOT, 256, 320, 320, 320);
    // y1 = xs @ W3a.T + b3
    gemm_bf<float, 0><<<dim3(2, 256), 256, 0, stream>>>(
        xsb, W3ab, b3, y1, BN_TOT, 256, 256, 256, 256);

    edge_gather<<<BN_TOT, 256, 0, stream>>>(edat, noff, y1, edge_attr, agg1, eaggb);
    gemm_bf<float, 0><<<dim3(2, 256), 256, 0, stream>>>(
        eaggb, Mb, nullptr, aggM, BN_TOT, 256, 64, 64, 64);

    gcn_finalize<<<BN_TOT / 4, 256, 0, stream>>>(agg1, aggM, y1, sb, deg, gcn_bias, lenc);

    bn_stats<<<512, 256, 0, stream>>>(h, stats, stats + 256, BN_TOT);
    bn_apply<<<BN_TOT / 4, 256, 0, stream>>>(h, stats, stats + 256, bn1_g, bn1_b, BN_TOT, hb);

    gemm_bf<bf16, 0><<<dim3(6, 256), 256, 0, stream>>>(
        hb, ipwb, in_proj_b, qkv, BN_TOT, 768, 256, 256, 256);

    attn_mfma<<<BB * 4 * 4, 512, 0, stream>>>(qkv, attnoutb);

    gemm_bf<float, 0><<<dim3(2, 256), 256, 0, stream>>>(
        attnoutb, opwb, out_proj_b, attnp, BN_TOT, 256, 256, 256, 256);

    add_ln_kernel<<<BN_TOT / 4, 256, 0, stream>>>(h, attnp, ln1_g, ln1_b, h1, h1b);

    gemm_bf<bf16, 1><<<dim3(8, 256), 256, 0, stream>>>(
        h1b, l1wb, lin1_b, ffa, BN_TOT, 1024, 256, 256, 256);
    gemm_bf<float, 0><<<dim3(2, 256), 256, 0, stream>>>(
        (const u16*)ffa, l2wb, lin2_b, ffb, BN_TOT, 256, 1024, 1024, 1024);

    add_ln_kernel<<<BN_TOT / 4, 256, 0, stream>>>(h1, ffb, ln2_g, ln2_b, h2, nullptr);

    bn_stats<<<512, 256, 0, stream>>>(h2, stats + 512, stats + 768, BN_TOT);
    bn_apply<<<BN_TOT / 4, 256, 0, stream>>>(h2, stats + 512, stats + 768, bn2_g, bn2_b, BN_TOT, nullptr);

    pool_kernel<<<64, 256, 0, stream>>>(h2, lenc, poolbuf);
    head_kernel<<<1, 64, 0, stream>>>(poolbuf, lin_w, lin_b, bn3_g, bn3_b, (float*)d_out);
}

// Round 9
// 687.082 us; speedup vs baseline: 1.0174x; 1.0174x over previous
//
#include <hip/hip_runtime.h>
#include <hip/hip_bf16.h>

// Shapes
#define BB   64
#define NN   512
#define EE   2048
#define FINK 300
#define DD   256
#define BN_TOT (BB*NN)    // 32768
#define BE_TOT (BB*EE)    // 131072
#define EPSF 1e-5f

using bf16 = __hip_bfloat16;
typedef unsigned short u16;
typedef __attribute__((ext_vector_type(8))) short short8;
typedef __attribute__((ext_vector_type(4))) float f32x4;
typedef __attribute__((ext_vector_type(4))) unsigned short u16x4;

__device__ __forceinline__ float tf(float x) { return x; }
__device__ __forceinline__ float tf(bf16 x)  { return __bfloat162float(x); }
__device__ __forceinline__ void  stv(float* p, float v) { *p = v; }
__device__ __forceinline__ void  stv(bf16*  p, float v) { *p = __float2bfloat16(v); }

__device__ __forceinline__ u16 f2bu(float f) {
    bf16 b = __float2bfloat16(f);
    return *(u16*)&b;
}
// f32x4 -> 4x bf16 stored as one 8B write
__device__ __forceinline__ void st4b(u16* p, f32x4 v)
{
    u16x4 o;
    o[0] = f2bu(v[0]); o[1] = f2bu(v[1]); o[2] = f2bu(v[2]); o[3] = f2bu(v[3]);
    *(u16x4*)p = o;
}

// Direct global->LDS DMA, 16B per lane. LDS dst = wave-uniform base + lane*16.
__device__ __forceinline__ void gload16(const void* g, void* l)
{
    __builtin_amdgcn_global_load_lds((const __attribute__((address_space(1))) void*)g,
                                     (__attribute__((address_space(3))) void*)l, 16, 0, 0);
}

// Int dtype probe: lengths[1] as int32 is in [256,512] iff int32 storage;
// it is the zero hi-word of lengths[0] iff int64 (LE).
__global__ void detect_kernel(const int* __restrict__ lengths, int* __restrict__ flags)
{
    flags[1] = (lengths[1] == 0) ? 1 : 0;
}

__global__ void conv_i(const void* __restrict__ src, int* __restrict__ dst, int n,
                       const int* __restrict__ flags)
{
    int i = blockIdx.x * 256 + threadIdx.x;
    if (i >= n) return;
    const int* s = (const int*)src;
    dst[i] = s[flags[1] ? (i << 1) : i];
}

// both edge-index conversions in one launch
__global__ void conv_i2(const void* __restrict__ src1, int* __restrict__ dst1,
                        const void* __restrict__ src2, int* __restrict__ dst2,
                        int n, const int* __restrict__ flags)
{
    int i = blockIdx.x * 256 + threadIdx.x;
    int wide = flags[1];
    if (i < n) {
        dst1[i] = ((const int*)src1)[wide ? (i << 1) : i];
    } else if (i < 2 * n) {
        int k = i - n;
        dst2[k] = ((const int*)src2)[wide ? (k << 1) : k];
    }
}

// f32 (rows x sk) -> bf16 (rows x dk) zero-padded, 4 cols/thread.
__global__ void conv_pad(const float* __restrict__ src, u16* __restrict__ dst, int rows,
                         int sk, int dk)
{
    int dk4 = dk >> 2;
    int i = blockIdx.x * 256 + threadIdx.x;
    if (i >= rows * dk4) return;
    int r = i / dk4, c4 = (i - r * dk4) * 4;
    if (c4 < sk) {
        f32x4 v = *(const f32x4*)&src[(size_t)r * sk + c4];
        st4b(&dst[(size_t)r * dk + c4], v);
    } else {
        *(u16x4*)&dst[(size_t)r * dk + c4] = (u16x4){0, 0, 0, 0};
    }
}

// all four plain f32->bf16 weight conversions in one launch (quad ranges:
// ipw 49152, opw 16384, l1w 65536, l2w 65536 -> 196608 quads, 768 blocks)
__global__ void conv_w4(const float* __restrict__ s0, u16* __restrict__ d0,
                        const float* __restrict__ s1, u16* __restrict__ d1,
                        const float* __restrict__ s2, u16* __restrict__ d2,
                        const float* __restrict__ s3, u16* __restrict__ d3)
{
    int i = blockIdx.x * 256 + threadIdx.x;
    const float* s; u16* d; int off;
    if (i < 49152)       { s = s0; d = d0; off = i; }
    else if (i < 65536)  { s = s1; d = d1; off = i - 49152; }
    else if (i < 131072) { s = s2; d = d2; off = i - 65536; }
    else                 { s = s3; d = d3; off = i - 131072; }
    f32x4 v = *(const f32x4*)&s[(size_t)off * 4];
    st4b(&d[(size_t)off * 4], v);
}

// W13 = W3[:, :256] @ W1  (256 x 320 bf16, zero-padded cols 300..319).
// Folds the xs = x@W1.T GEMM into y1 = x@W13.T (+b3).
__global__ void prep_W13(const float* __restrict__ W3, const float* __restrict__ W1,
                         u16* __restrict__ W13b)
{
    int d = blockIdx.x;      // 0..255
    int f = threadIdx.x;     // 0..319
    float s = 0.f;
    if (f < FINK) {
        for (int j = 0; j < 256; j++)
            s += W3[d * 512 + j] * W1[j * FINK + f];
    }
    W13b[d * 320 + f] = f2bu(s);
}

// ---------------------------------------------------------------------------
// m97-style MFMA GEMM: C[m,n] = sum_k A[m,k]*W[n*ldw+k] (+bias,+relu)
// A, W bf16 (u16) row-major; tile 128x128, 4 waves, K-step 32.
// Staging via global_load_lds width=16 into unpadded [128][32] LDS tiles
// (DMA writes lane i at base + i*16B -> rows packed 4 lanes/row).
// M,N multiples of 128; K multiple of 32; lda/ldw elems, rows 16B-aligned.
// ---------------------------------------------------------------------------
template<typename TC, int RELU>
__global__ __launch_bounds__(256)
void gemm_bf(const u16* __restrict__ A, const u16* __restrict__ W,
             const float* __restrict__ bias, TC* __restrict__ C,
             int M, int N, int K, int lda, int ldw)
{
    __shared__ u16 As[128 * 32];
    __shared__ u16 Ws[128 * 32];

    const int m0 = blockIdx.y * 128;
    const int n0 = blockIdx.x * 128;
    const int tid  = threadIdx.x;
    const int lane = tid & 63;
    const int wv   = tid >> 6;
    const int fr   = lane & 15;
    const int q8   = (lane >> 4) * 8;
    const int mb   = (wv >> 1) * 64;
    const int nb   = (wv & 1) * 64;

    const int r16 = lane >> 2;          // 0..15 (staging row within 16-row group)
    const int c8  = (lane & 3) * 8;     // 0,8,16,24 (k sub-offset)

    f32x4 acc[4][4];
#pragma unroll
    for (int i = 0; i < 4; i++)
#pragma unroll
        for (int j = 0; j < 4; j++) acc[i][j] = (f32x4){0.f, 0.f, 0.f, 0.f};

    for (int k0 = 0; k0 < K; k0 += 32) {
        __syncthreads();
#pragma unroll
        for (int j = 0; j < 2; j++) {
            int rowA = m0 + wv * 32 + j * 16 + r16;
            int rowW = n0 + wv * 32 + j * 16 + r16;
            gload16(A + (size_t)rowA * lda + k0 + c8, &As[(wv * 32 + j * 16) * 32]);
            gload16(W + (size_t)rowW * ldw + k0 + c8, &Ws[(wv * 32 + j * 16) * 32]);
        }
        __syncthreads();

        short8 af[4], bf[4];
#pragma unroll
        for (int i = 0; i < 4; i++) af[i] = *(const short8*)&As[(mb + i * 16 + fr) * 32 + q8];
#pragma unroll
        for (int j = 0; j < 4; j++) bf[j] = *(const short8*)&Ws[(nb + j * 16 + fr) * 32 + q8];
#pragma unroll
        for (int i = 0; i < 4; i++)
#pragma unroll
            for (int j = 0; j < 4; j++)
                acc[i][j] = __builtin_amdgcn_mfma_f32_16x16x32_bf16(af[i], bf[j], acc[i][j], 0, 0, 0);
    }

#pragma unroll
    for (int i = 0; i < 4; i++) {
#pragma unroll
        for (int j = 0; j < 4; j++) {
            int gn = n0 + nb + j * 16 + fr;
            float bv = bias ? bias[gn] : 0.f;
#pragma unroll
            for (int r = 0; r < 4; r++) {
                int gm = m0 + mb + i * 16 + (lane >> 4) * 4 + r;
                float v = acc[i][j][r] + bv;
                if (RELU) v = fmaxf(v, 0.f);
                stv(&C[(size_t)gm * N + gn], v);
            }
        }
    }
}

// M = W3b @ W2 (256 x 64) f32+bf16; sb[d] = row-sum of W3b.
__global__ void prep_M(const float* __restrict__ W3, const float* __restrict__ W2,
                       u16* __restrict__ Mb, float* __restrict__ sb)
{
    int d = blockIdx.x, a = threadIdx.x;
    float s = 0.f;
    for (int j = 0; j < 256; j++)
        s += W3[d * 512 + 256 + j] * W2[j * 64 + a];
    Mb[d * 64 + a] = f2bu(s);
    if (a == 0) {
        float t = 0.f;
        for (int j = 0; j < 256; j++) t += W3[d * 512 + 256 + j];
        sb[d] = t;
    }
}

// ---------------------------------------------------------------------------
// Per-batch counting sort of edges by column. One block per batch, 512 thr.
// v2: emits flattened per-slot records edat = {(e<<16)|row, norm} so the
// gather kernel has NO pointer chase (norm computed here from LDS counts).
// ---------------------------------------------------------------------------
__global__ __launch_bounds__(512)
void sort_edges(const int* __restrict__ ecol, const int* __restrict__ erow,
                float* __restrict__ deg, int* __restrict__ node_off,
                uint2* __restrict__ edat)
{
    const int b = blockIdx.x;
    const int t = threadIdx.x;
    const int base = b * EE;
    __shared__ int cnt[512];
    __shared__ int tmp[512];
    __shared__ int off2[512];

    cnt[t] = 0;
    __syncthreads();
    for (int e = t; e < EE; e += 512) atomicAdd(&cnt[ecol[base + e]], 1);
    __syncthreads();

    int v = cnt[t];
    deg[b * NN + t] = (float)(v + 1);
    tmp[t] = v;
    __syncthreads();
    for (int s = 1; s < 512; s <<= 1) {
        int y = (t >= s) ? tmp[t - s] : 0;
        __syncthreads();
        tmp[t] += y;
        __syncthreads();
    }
    int excl = tmp[t] - v;
    node_off[b * NN + t] = excl;
    off2[t] = excl;
    __syncthreads();
    for (int e = t; e < EE; e += 512) {
        int c = ecol[base + e];
        int r = erow[base + e];
        int pos = atomicAdd(&off2[c], 1);
        float nrm = rsqrtf((float)((cnt[r] + 1) * (cnt[c] + 1)));
        edat[base + pos] = make_uint2(((unsigned)e << 16) | (unsigned)r,
                                      __float_as_uint(nrm));
    }
}

// ---------------------------------------------------------------------------
// Gather aggregation v2 (no atomics, no pointer chase): one block per node.
// ---------------------------------------------------------------------------
__global__ __launch_bounds__(256)
void edge_gather(const uint2* __restrict__ edat, const int* __restrict__ node_off,
                 const float* __restrict__ y1, const float* __restrict__ eattr,
                 float* __restrict__ agg1, u16* __restrict__ eaggb)
{
    const int j = blockIdx.x;
    const int b = j >> 9;
    const int cc = j & 511;
    const int tid  = threadIdx.x;
    const int wv   = tid >> 6;
    const int lane = tid & 63;
    const int start = node_off[j];
    const int end   = (cc == 511) ? EE : node_off[j + 1];

    f32x4 acc = (f32x4){0.f, 0.f, 0.f, 0.f};
    float acce = 0.f;
    for (int i = start + wv; i < end; i += 4) {
        uint2 ed = edat[(size_t)b * EE + i];
        float nw = __uint_as_float(ed.y);
        int r = (int)(ed.x & 0xffffu);
        int e = (int)(ed.x >> 16);
        f32x4 yv = *(const f32x4*)&y1[((size_t)(b * NN + r)) * 256 + lane * 4];
        acc += nw * yv;
        acce += nw * eattr[((size_t)(b * EE + e)) * 64 + lane];
    }

    __shared__ f32x4 redA[4][64];
    __shared__ float redB[4][64];
    redA[wv][lane] = acc;
    redB[wv][lane] = acce;
    __syncthreads();
    if (tid < 64) {
        f32x4 s = redA[0][tid];
        float se = redB[0][tid];
#pragma unroll
        for (int w = 1; w < 4; w++) { s += redA[w][tid]; se += redB[w][tid]; }
        *(f32x4*)&agg1[(size_t)j * 256 + tid * 4] = s;
        eaggb[(size_t)j * 64 + tid] = f2bu(se);
    }
}

// h = tanh((agg1 + aggM + (y1+sb)/deg)/deg + bias) * mask -> aggM in place
__global__ void gcn_finalize(const float* __restrict__ agg1, float* __restrict__ aggM,
                             const float* __restrict__ y1, const float* __restrict__ sb,
                             const float* __restrict__ deg, const float* __restrict__ gcn_bias,
                             const int* __restrict__ lengths)
{
    int idx4 = blockIdx.x * 256 + threadIdx.x;       // group-of-4 index
    int j  = idx4 >> 6;
    int d4 = (idx4 & 63) * 4;
    size_t base = (size_t)j * 256 + d4;
    float dg = deg[j];
    float inv = 1.f / dg;
    f32x4 a1 = *(const f32x4*)&agg1[base];
    f32x4 aM = *(const f32x4*)&aggM[base];
    f32x4 yv = *(const f32x4*)&y1[base];
    f32x4 sv = *(const f32x4*)&sb[d4];
    f32x4 gb = *(const f32x4*)&gcn_bias[d4];
    int b = j >> 9, p = j & 511;
    bool live = (p < lengths[b]);
    f32x4 o;
#pragma unroll
    for (int k = 0; k < 4; k++) {
        float a = (a1[k] + aM[k] + (yv[k] + sv[k]) * inv) * inv;
        o[k] = live ? tanhf(a + gb[k]) : 0.f;
    }
    *(f32x4*)&aggM[base] = o;
}

__global__ void bn_stats(const float* __restrict__ X, float* __restrict__ sums,
                         float* __restrict__ sumsq, int R)
{
    int wv = threadIdx.x >> 6, lane = threadIdx.x & 63;
    f32x4 s = (f32x4){0.f, 0.f, 0.f, 0.f};
    f32x4 q = (f32x4){0.f, 0.f, 0.f, 0.f};
    for (int r = blockIdx.x * 4 + wv; r < R; r += gridDim.x * 4) {
        f32x4 v = *(const f32x4*)&X[(size_t)r * DD + lane * 4];
        s += v; q += v * v;
    }
    __shared__ f32x4 rs[4][64], rq[4][64];
    rs[wv][lane] = s; rq[wv][lane] = q;
    __syncthreads();
    if (threadIdx.x < 64) {
        f32x4 ts = rs[0][lane], tq = rq[0][lane];
#pragma unroll
        for (int w = 1; w < 4; w++) { ts += rs[w][lane]; tq += rq[w][lane]; }
#pragma unroll
        for (int k = 0; k < 4; k++) {
            atomicAdd(&sums[lane * 4 + k], ts[k]);
            atomicAdd(&sumsq[lane * 4 + k], tq[k]);
        }
    }
}

// X normalized in place; optional bf16 duplicate. f32x4 / 4 per thread.
__global__ void bn_apply(float* __restrict__ X, const float* __restrict__ sums,
                         const float* __restrict__ sumsq, const float* __restrict__ g,
                         const float* __restrict__ bt, int R, u16* __restrict__ dup)
{
    int idx4 = blockIdx.x * 256 + threadIdx.x;
    int d4 = (idx4 & 63) * 4;
    size_t base = (size_t)idx4 * 4;
    float invR = 1.f / (float)R;
    f32x4 sm = *(const f32x4*)&sums[d4];
    f32x4 sq = *(const f32x4*)&sumsq[d4];
    f32x4 gv = *(const f32x4*)&g[d4];
    f32x4 bv = *(const f32x4*)&bt[d4];
    f32x4 x  = *(const f32x4*)&X[base];
    f32x4 o;
#pragma unroll
    for (int k = 0; k < 4; k++) {
        float m   = sm[k] * invR;
        float var = sq[k] * invR - m * m;
        o[k] = (x[k] - m) * rsqrtf(fmaxf(var, 0.f) + EPSF) * gv[k] + bv[k];
    }
    *(f32x4*)&X[base] = o;
    if (dup) st4b(&dup[base], o);
}

// ---------------------------------------------------------------------------
// MFMA flash attention. v6: 512-thread blocks, 8 waves, 128 q-rows per
// block; grid 1024, qp = bid>>8 XCD-coherent. Ps is WAVE-LOCAL (each wave
// writes/reads only its 16 rows), so PV runs in two 64-col halves reusing a
// [128][68] Ps: LDS 71.1 -> 52 KB -> 3 blocks/CU (24 waves, vs 16).
// Stride 68 (34 dwords) makes P-stores exactly conflict-free (4 quads x
// 8-bank groups cover all 32 banks). No added synchronization.
// ---------------------------------------------------------------------------
__global__ __launch_bounds__(512, 2)
void attn_mfma(const bf16* __restrict__ qkv, u16* __restrict__ out)
{
    const int bid = blockIdx.x;
    const int qp = bid >> 8;        // 0..3 (slow bits -> XCD-coherent (b,h))
    const int pr = bid & 255;
    const int h  = pr & 3;
    const int b  = pr >> 2;

    const int tid  = threadIdx.x;
    const int lane = tid & 63;
    const int wv   = tid >> 6;      // 0..7
    const int fr   = lane & 15;
    const int quad = lane >> 4;
    const int q8   = quad * 8;

    __shared__ u16 Ks[128][72];
    __shared__ u16 Vts[64][136];
    __shared__ u16 Ps[128][68];

    const u16* qb = (const u16*)qkv;
    const size_t bb = (size_t)(b * NN);
    const float CE = 0.125f * 1.44269504f;   // softmax scale folded into exp2

    // Q fragments in registers: wave wv owns q-rows qp*128 + wv*16 + fr.
    short8 aq[2];
#pragma unroll
    for (int ks = 0; ks < 2; ks++)
        aq[ks] = *(const short8*)(qb + (bb + qp * 128 + wv * 16 + fr) * 768
                                  + h * 64 + ks * 32 + q8);

    f32x4 O[4];
    float m_i[4], l_i[4];
#pragma unroll
    for (int t = 0; t < 4; t++) {
        O[t] = (f32x4){0.f, 0.f, 0.f, 0.f};
        m_i[t] = -1e30f; l_i[t] = 0.f;
    }

    for (int c = 0; c < 4; c++) {
        __syncthreads();            // previous chunk's LDS reads complete
#pragma unroll
        for (int i = 0; i < 2; i++) {
            int idx = i * 512 + tid;
            int r = idx >> 3, seg = idx & 7;
            uint4 u = *((const uint4*)(qb + (bb + c * 128 + r) * 768 + 256 + h * 64) + seg);
            *(uint4*)&Ks[r][seg * 8] = u;
            uint4 v = *((const uint4*)(qb + (bb + c * 128 + r) * 768 + 512 + h * 64) + seg);
            // V^T store, 16B-granular XOR swizzle (seg == d>>3 for all 8 elems)
            u16* dst = &Vts[seg * 8][r ^ (seg << 3)];
            dst[0*136] = (u16)(v.x & 0xffff); dst[1*136] = (u16)(v.x >> 16);
            dst[2*136] = (u16)(v.y & 0xffff); dst[3*136] = (u16)(v.y >> 16);
            dst[4*136] = (u16)(v.z & 0xffff); dst[5*136] = (u16)(v.z >> 16);
            dst[6*136] = (u16)(v.w & 0xffff); dst[7*136] = (u16)(v.w >> 16);
        }
        __syncthreads();

        f32x4 S[8];
#pragma unroll
        for (int t = 0; t < 8; t++) S[t] = (f32x4){0.f, 0.f, 0.f, 0.f};
        __builtin_amdgcn_s_setprio(1);
#pragma unroll
        for (int ks = 0; ks < 2; ks++) {
#pragma unroll
            for (int t = 0; t < 8; t++) {
                short8 bk = *(const short8*)&Ks[t * 16 + fr][ks * 32 + q8];
                S[t] = __builtin_amdgcn_mfma_f32_16x16x32_bf16(aq[ks], bk, S[t], 0, 0, 0);
            }
        }
        __builtin_amdgcn_s_setprio(0);

        float mc[4];
#pragma unroll
        for (int r = 0; r < 4; r++) {
            float mm = -1e30f;
#pragma unroll
            for (int t = 0; t < 8; t++) mm = fmaxf(mm, S[t][r]);
            mc[r] = mm;
        }
#pragma unroll
        for (int msk = 1; msk < 16; msk <<= 1)
#pragma unroll
            for (int r = 0; r < 4; r++) mc[r] = fmaxf(mc[r], __shfl_xor(mc[r], msk));

        float alpha[4], ls[4];
#pragma unroll
        for (int r = 0; r < 4; r++) {
            float mn = fmaxf(m_i[r], mc[r]);
            alpha[r] = __builtin_amdgcn_exp2f((m_i[r] - mn) * CE);
            m_i[r] = mn;
            ls[r] = 0.f;
        }
        // rescale O before accumulating this chunk's PV
#pragma unroll
        for (int t = 0; t < 4; t++)
#pragma unroll
            for (int r = 0; r < 4; r++) O[t][r] *= alpha[r];

        // two 64-col halves: write P (wave-local), then PV on that half
#pragma unroll
        for (int hf = 0; hf < 2; hf++) {
#pragma unroll
            for (int tl = 0; tl < 4; tl++) {
                int t = hf * 4 + tl;
#pragma unroll
                for (int r = 0; r < 4; r++) {
                    float p = __builtin_amdgcn_exp2f((S[t][r] - m_i[r]) * CE);
                    Ps[wv * 16 + quad * 4 + r][tl * 16 + fr] = f2bu(p);
                    ls[r] += p;
                }
            }
            __builtin_amdgcn_s_setprio(1);
#pragma unroll
            for (int ks = 0; ks < 2; ks++) {
                short8 ap = *(const short8*)&Ps[wv * 16 + fr][ks * 32 + q8];
                int g = hf * 2 + ks;
#pragma unroll
                for (int t = 0; t < 4; t++) {
                    short8 bv = *(const short8*)&Vts[t * 16 + fr]
                                    [(g * 32 + q8) ^ ((t * 2 + (fr >> 3)) << 3)];
                    O[t] = __builtin_amdgcn_mfma_f32_16x16x32_bf16(ap, bv, O[t], 0, 0, 0);
                }
            }
            __builtin_amdgcn_s_setprio(0);
        }

#pragma unroll
        for (int msk = 1; msk < 16; msk <<= 1)
#pragma unroll
            for (int r = 0; r < 4; r++) ls[r] += __shfl_xor(ls[r], msk);
#pragma unroll
        for (int r = 0; r < 4; r++) l_i[r] = l_i[r] * alpha[r] + ls[r];
    }

#pragma unroll
    for (int t = 0; t < 4; t++)
#pragma unroll
        for (int r = 0; r < 4; r++) {
            int q = qp * 128 + wv * 16 + quad * 4 + r;
            out[(bb + q) * 256 + h * 64 + t * 16 + fr] = f2bu(O[t][r] / l_i[r]);
        }
}

// out = LN(X + Y); optional bf16 duplicate. One wave per row, zero barriers.
__global__ void add_ln_kernel(const float* __restrict__ X, const float* __restrict__ Y,
                              const float* __restrict__ g, const float* __restrict__ bt,
                              float* __restrict__ out, u16* __restrict__ dup)
{
    int wv = threadIdx.x >> 6, lane = threadIdx.x & 63;
    int row = blockIdx.x * 4 + wv;
    size_t base = (size_t)row * DD + lane * 4;
    f32x4 v = *(const f32x4*)&X[base] + *(const f32x4*)&Y[base];
    float s = v[0] + v[1] + v[2] + v[3];
#pragma unroll
    for (int m = 1; m < 64; m <<= 1) s += __shfl_xor(s, m);
    float mean = s * (1.f / DD);
    f32x4 d;
#pragma unroll
    for (int k = 0; k < 4; k++) d[k] = v[k] - mean;
    float q = d[0]*d[0] + d[1]*d[1] + d[2]*d[2] + d[3]*d[3];
#pragma unroll
    for (int m = 1; m < 64; m <<= 1) q += __shfl_xor(q, m);
    float inv = rsqrtf(q * (1.f / DD) + EPSF);
    f32x4 gv = *(const f32x4*)&g[lane * 4];
    f32x4 bv = *(const f32x4*)&bt[lane * 4];
    f32x4 o;
#pragma unroll
    for (int k = 0; k < 4; k++) o[k] = d[k] * inv * gv[k] + bv[k];
    *(f32x4*)&out[base] = o;
    if (dup) st4b(&dup[base], o);
}

__global__ void pool_kernel(const float* __restrict__ enc, const int* __restrict__ lengths,
                            float* __restrict__ poolbuf)
{
    int b = blockIdx.x;
    int wv = threadIdx.x >> 6, lane = threadIdx.x & 63;
    int L = lengths[b];
    if (L < 1) L = 1;
    f32x4 s  = (f32x4){0.f, 0.f, 0.f, 0.f};
    f32x4 mx = (f32x4){-1e30f, -1e30f, -1e30f, -1e30f};
    for (int n = wv; n < NN; n += 4) {
        f32x4 v = *(const f32x4*)&enc[((size_t)b * NN + n) * DD + lane * 4];
        s += v;
        if (n < L) {
#pragma unroll
            for (int k = 0; k < 4; k++) mx[k] = fmaxf(mx[k], v[k]);
        }
    }
    __shared__ f32x4 rs[4][64], rm[4][64];
    rs[wv][lane] = s; rm[wv][lane] = mx;
    __syncthreads();
    if (threadIdx.x < 64) {
        f32x4 ts = rs[0][lane], tm = rm[0][lane];
#pragma unroll
        for (int w = 1; w < 4; w++) {
            ts += rs[w][lane];
#pragma unroll
            for (int k = 0; k < 4; k++) tm[k] = fmaxf(tm[k], rm[w][lane][k]);
        }
        float invL = 1.f / (float)L;
#pragma unroll
        for (int k = 0; k < 4; k++) {
            poolbuf[b * 512 + lane * 4 + k]       = tm[k];
            poolbuf[b * 512 + 256 + lane * 4 + k] = ts[k] * invL;
        }
    }
}

__global__ void head_kernel(const float* __restrict__ poolbuf, const float* __restrict__ lin_w,
                            const float* __restrict__ lin_b, const float* __restrict__ g,
                            const float* __restrict__ bt, float* __restrict__ out)
{
    int b = threadIdx.x;
    float r0 = lin_b[0], r1 = lin_b[1];
    for (int k = 0; k < 512; k++) {
        float p = poolbuf[b * 512 + k];
        r0 += p * lin_w[k];
        r1 += p * lin_w[512 + k];
    }
    __shared__ float s0[64], s1[64], mstat[4];
    s0[b] = r0; s1[b] = r1; __syncthreads();
    if (b == 0) {
        float a0 = 0, a1 = 0, q0 = 0, q1 = 0;
        for (int i = 0; i < 64; i++) { a0 += s0[i]; a1 += s1[i]; }
        a0 *= (1.f / 64.f); a1 *= (1.f / 64.f);
        for (int i = 0; i < 64; i++) {
            float d0 = s0[i] - a0, d1 = s1[i] - a1;
            q0 += d0 * d0; q1 += d1 * d1;
        }
        mstat[0] = a0; mstat[1] = a1; mstat[2] = q0 * (1.f / 64.f); mstat[3] = q1 * (1.f / 64.f);
    }
    __syncthreads();
    float z0 = (r0 - mstat[0]) * rsqrtf(mstat[2] + EPSF) * g[0] + bt[0];
    float z1 = (r1 - mstat[1]) * rsqrtf(mstat[3] + EPSF) * g[1] + bt[1];
    float mx = fmaxf(z0, z1);
    float e0 = __expf(z0 - mx), e1 = __expf(z1 - mx);
    float inv = 1.f / (e0 + e1);
    out[b * 2 + 0] = e0 * inv;
    out[b * 2 + 1] = e1 * inv;
}

extern "C" void kernel_launch(void* const* d_in, const int* in_sizes, int n_in,
                              void* d_out, int out_size, void* d_ws, size_t ws_size,
                              hipStream_t stream)
{
    (void)in_sizes; (void)n_in; (void)out_size; (void)ws_size;
    const float* x          = (const float*)d_in[0];
    const float* edge_attr  = (const float*)d_in[1];
    const float* W1         = (const float*)d_in[5];
    const float* W2         = (const float*)d_in[6];
    const float* W3         = (const float*)d_in[7];
    const float* b3         = (const float*)d_in[8];
    const float* gcn_bias   = (const float*)d_in[9];
    const float* bn1_g      = (const float*)d_in[10];
    const float* bn1_b      = (const float*)d_in[11];
    const float* in_proj_w  = (const float*)d_in[12];
    const float* in_proj_b  = (const float*)d_in[13];
    const float* out_proj_w = (const float*)d_in[14];
    const float* out_proj_b = (const float*)d_in[15];
    const float* ln1_g      = (const float*)d_in[16];
    const float* ln1_b      = (const float*)d_in[17];
    const float* lin1_w     = (const float*)d_in[18];
    const float* lin1_b     = (const float*)d_in[19];
    const float* lin2_w     = (const float*)d_in[20];
    const float* lin2_b     = (const float*)d_in[21];
    const float* ln2_g      = (const float*)d_in[22];
    const float* ln2_b      = (const float*)d_in[23];
    const float* bn2_g      = (const float*)d_in[24];
    const float* bn2_b      = (const float*)d_in[25];
    const float* lin_w      = (const float*)d_in[26];
    const float* lin_b      = (const float*)d_in[27];
    const float* bn3_g      = (const float*)d_in[28];
    const float* bn3_b      = (const float*)d_in[29];

    // ---- Workspace layout (~186 MB) ----
    char* p = (char*)d_ws;
    u16*   big   = (u16*)p;   p += (size_t)BN_TOT * 1024 * 2;   // 64 MiB: [xb|(unused)|eaggb] -> qkv -> ffa
    float* bufA  = (float*)p; p += (size_t)BN_TOT * 256 * 4;    // aggM/h -> ffb
    float* bufB  = (float*)p; p += (size_t)BN_TOT * 256 * 4;    // y1 -> attnp -> h2
    float* bufC  = (float*)p; p += (size_t)BN_TOT * 256 * 4;    // agg1 -> h1
    u16*   bufP  = (u16*)p;   p += (size_t)BN_TOT * 256 * 2;    // 16.8 MB: hb -> attnoutb -> h1b
    float* deg   = (float*)p; p += (size_t)BN_TOT * 4;
    u16*   Mb    = (u16*)p;   p += 256 * 64 * 2;
    float* sb    = (float*)p; p += 1024;
    float* stats = (float*)p; p += 4 * 256 * 4;
    float* poolbuf=(float*)p; p += 64 * 512 * 4;
    int*   flags = (int*)p;   p += 256;
    int*   erc   = (int*)p;   p += BE_TOT * 4;
    int*   ecc   = (int*)p;   p += BE_TOT * 4;
    int*   lenc  = (int*)p;   p += 256;
    uint2* edat  = (uint2*)p; p += (size_t)BE_TOT * 8;
    int*   noff  = (int*)p;   p += BN_TOT * 4;
    u16*   W13b  = (u16*)p;   p += 256 * 320 * 2;
    u16*   ipwb  = (u16*)p;   p += 768 * 256 * 2;
    u16*   opwb  = (u16*)p;   p += 256 * 256 * 2;
    u16*   l1wb  = (u16*)p;   p += 1024 * 256 * 2;
    u16*   l2wb  = (u16*)p;   p += 256 * 1024 * 2;

    // bf16 temporaries inside big (all dead before qkv is written at in_proj)
    u16* xb    = big;                              // 32768 x 320
    u16* eaggb = big + (size_t)BN_TOT * (320+256); // 32768 x 64
    bf16* qkv  = (bf16*)big;
    bf16* ffa  = (bf16*)big;

    float* y1      = bufB;
    float* agg1    = bufC;
    float* aggM    = bufA;    // becomes h in finalize
    float* h       = bufA;
    u16*   hb      = bufP;
    u16*   attnoutb= bufP;    // hb dead after in_proj GEMM
    float* attnp   = bufB;    // y1 dead after finalize
    float* h1      = bufC;    // agg1 dead after finalize
    u16*   h1b     = bufP;    // attnoutb dead after out_proj GEMM
    float* ffb     = bufA;    // h dead after add_ln #1
    float* h2      = bufB;    // attnp dead after add_ln #1

    hipMemsetAsync(stats, 0, 4 * 256 * 4, stream);

    detect_kernel<<<1, 1, 0, stream>>>((const int*)d_in[4], flags);
    conv_i2<<<(2 * BE_TOT + 255) / 256, 256, 0, stream>>>(d_in[2], erc, d_in[3], ecc,
                                                          BE_TOT, flags);
    conv_i<<<1, 64, 0, stream>>>(d_in[4], lenc, BB, flags);

    // input conversion + fused weight conversions
    conv_pad<<<(BN_TOT * 80 + 255) / 256, 256, 0, stream>>>(x, xb, BN_TOT, FINK, 320);
    conv_w4<<<768, 256, 0, stream>>>(in_proj_w, ipwb, out_proj_w, opwb,
                                     lin1_w, l1wb, lin2_w, l2wb);

    prep_W13<<<256, 320, 0, stream>>>(W3, W1, W13b);
    prep_M<<<256, 64, 0, stream>>>(W3, W2, Mb, sb);
    sort_edges<<<BB, 512, 0, stream>>>(ecc, erc, deg, noff, edat);

    // y1 = x @ (W3a@W1).T + b3  (xs GEMM folded into the weight)
    gemm_bf<float, 0><<<dim3(2, 256), 256, 0, stream>>>(
        xb, W13b, b3, y1, BN_TOT, 256, 320, 320, 320);

    edge_gather<<<BN_TOT, 256, 0, stream>>>(edat, noff, y1, edge_attr, agg1, eaggb);
    gemm_bf<float, 0><<<dim3(2, 256), 256, 0, stream>>>(
        eaggb, Mb, nullptr, aggM, BN_TOT, 256, 64, 64, 64);

    gcn_finalize<<<BN_TOT / 4, 256, 0, stream>>>(agg1, aggM, y1, sb, deg, gcn_bias, lenc);

    bn_stats<<<512, 256, 0, stream>>>(h, stats, stats + 256, BN_TOT);
    bn_apply<<<BN_TOT / 4, 256, 0, stream>>>(h, stats, stats + 256, bn1_g, bn1_b, BN_TOT, hb);

    gemm_bf<bf16, 0><<<dim3(6, 256), 256, 0, stream>>>(
        hb, ipwb, in_proj_b, qkv, BN_TOT, 768, 256, 256, 256);

    attn_mfma<<<BB * 4 * 4, 512, 0, stream>>>(qkv, attnoutb);

    gemm_bf<float, 0><<<dim3(2, 256), 256, 0, stream>>>(
        attnoutb, opwb, out_proj_b, attnp, BN_TOT, 256, 256, 256, 256);

    add_ln_kernel<<<BN_TOT / 4, 256, 0, stream>>>(h, attnp, ln1_g, ln1_b, h1, h1b);

    gemm_bf<bf16, 1><<<dim3(8, 256), 256, 0, stream>>>(
        h1b, l1wb, lin1_b, ffa, BN_TOT, 1024, 256, 256, 256);
    gemm_bf<float, 0><<<dim3(2, 256), 256, 0, stream>>>(
        (const u16*)ffa, l2wb, lin2_b, ffb, BN_TOT, 256, 1024, 1024, 1024);

    add_ln_kernel<<<BN_TOT / 4, 256, 0, stream>>>(h1, ffb, ln2_g, ln2_b, h2, nullptr);

    bn_stats<<<512, 256, 0, stream>>>(h2, stats + 512, stats + 768, BN_TOT);
    bn_apply<<<BN_TOT / 4, 256, 0, stream>>>(h2, stats + 512, stats + 768, bn2_g, bn2_b, BN_TOT, nullptr);

    pool_kernel<<<64, 256, 0, stream>>>(h2, lenc, poolbuf);
    head_kernel<<<1, 64, 0, stream>>>(poolbuf, lin_w, lin_b, bn3_g, bn3_b, (float*)d_out);
}

// Round 10
// 593.513 us; speedup vs baseline: 1.1778x; 1.1577x over previous
//
#include <hip/hip_runtime.h>
#include <hip/hip_bf16.h>

// Shapes
#define BB   64
#define NN   512
#define EE   2048
#define FINK 300
#define DD   256
#define BN_TOT (BB*NN)    // 32768
#define BE_TOT (BB*EE)    // 131072
#define EPSF 1e-5f

using bf16 = __hip_bfloat16;
typedef unsigned short u16;
typedef __attribute__((ext_vector_type(8))) short short8;
typedef __attribute__((ext_vector_type(4))) float f32x4;
typedef __attribute__((ext_vector_type(4))) unsigned short u16x4;

__device__ __forceinline__ float tf(float x) { return x; }
__device__ __forceinline__ float tf(bf16 x)  { return __bfloat162float(x); }
__device__ __forceinline__ void  stv(float* p, float v) { *p = v; }
__device__ __forceinline__ void  stv(bf16*  p, float v) { *p = __float2bfloat16(v); }

__device__ __forceinline__ u16 f2bu(float f) {
    bf16 b = __float2bfloat16(f);
    return *(u16*)&b;
}
// f32x4 -> 4x bf16 stored as one 8B write
__device__ __forceinline__ void st4b(u16* p, f32x4 v)
{
    u16x4 o;
    o[0] = f2bu(v[0]); o[1] = f2bu(v[1]); o[2] = f2bu(v[2]); o[3] = f2bu(v[3]);
    *(u16x4*)p = o;
}

// Direct global->LDS DMA, 16B per lane. LDS dst = wave-uniform base + lane*16.
__device__ __forceinline__ void gload16(const void* g, void* l)
{
    __builtin_amdgcn_global_load_lds((const __attribute__((address_space(1))) void*)g,
                                     (__attribute__((address_space(3))) void*)l, 16, 0, 0);
}

// Int dtype probe: lengths[1] as int32 is in [256,512] iff int32 storage;
// it is the zero hi-word of lengths[0] iff int64 (LE).
__global__ void detect_kernel(const int* __restrict__ lengths, int* __restrict__ flags)
{
    flags[1] = (lengths[1] == 0) ? 1 : 0;
}

__global__ void conv_i(const void* __restrict__ src, int* __restrict__ dst, int n,
                       const int* __restrict__ flags)
{
    int i = blockIdx.x * 256 + threadIdx.x;
    if (i >= n) return;
    const int* s = (const int*)src;
    dst[i] = s[flags[1] ? (i << 1) : i];
}

// both edge-index conversions in one launch
__global__ void conv_i2(const void* __restrict__ src1, int* __restrict__ dst1,
                        const void* __restrict__ src2, int* __restrict__ dst2,
                        int n, const int* __restrict__ flags)
{
    int i = blockIdx.x * 256 + threadIdx.x;
    int wide = flags[1];
    if (i < n) {
        dst1[i] = ((const int*)src1)[wide ? (i << 1) : i];
    } else if (i < 2 * n) {
        int k = i - n;
        dst2[k] = ((const int*)src2)[wide ? (k << 1) : k];
    }
}

// f32 (rows x sk) -> bf16 (rows x dk) zero-padded, 4 cols/thread.
__global__ void conv_pad(const float* __restrict__ src, u16* __restrict__ dst, int rows,
                         int sk, int dk)
{
    int dk4 = dk >> 2;
    int i = blockIdx.x * 256 + threadIdx.x;
    if (i >= rows * dk4) return;
    int r = i / dk4, c4 = (i - r * dk4) * 4;
    if (c4 < sk) {
        f32x4 v = *(const f32x4*)&src[(size_t)r * sk + c4];
        st4b(&dst[(size_t)r * dk + c4], v);
    } else {
        *(u16x4*)&dst[(size_t)r * dk + c4] = (u16x4){0, 0, 0, 0};
    }
}

// all four plain f32->bf16 weight conversions in one launch (quad ranges:
// ipw 49152, opw 16384, l1w 65536, l2w 65536 -> 196608 quads, 768 blocks)
__global__ void conv_w4(const float* __restrict__ s0, u16* __restrict__ d0,
                        const float* __restrict__ s1, u16* __restrict__ d1,
                        const float* __restrict__ s2, u16* __restrict__ d2,
                        const float* __restrict__ s3, u16* __restrict__ d3)
{
    int i = blockIdx.x * 256 + threadIdx.x;
    const float* s; u16* d; int off;
    if (i < 49152)       { s = s0; d = d0; off = i; }
    else if (i < 65536)  { s = s1; d = d1; off = i - 49152; }
    else if (i < 131072) { s = s2; d = d2; off = i - 65536; }
    else                 { s = s3; d = d3; off = i - 131072; }
    f32x4 v = *(const f32x4*)&s[(size_t)off * 4];
    st4b(&d[(size_t)off * 4], v);
}

// W13 = W3[:, :256] @ W1  (256 x 320 bf16, zero-padded cols 300..319).
// Folds the xs = x@W1.T GEMM into y1 = x@W13.T (+b3).
__global__ void prep_W13(const float* __restrict__ W3, const float* __restrict__ W1,
                         u16* __restrict__ W13b)
{
    int d = blockIdx.x;      // 0..255
    int f = threadIdx.x;     // 0..319
    float s = 0.f;
    if (f < FINK) {
        for (int j = 0; j < 256; j++)
            s += W3[d * 512 + j] * W1[j * FINK + f];
    }
    W13b[d * 320 + f] = f2bu(s);
}

// ---------------------------------------------------------------------------
// m97-style MFMA GEMM: C[m,n] = sum_k A[m,k]*W[n*ldw+k] (+bias,+relu)
// A, W bf16 (u16) row-major; tile 128x128, 4 waves, K-step 32.
// Staging via global_load_lds width=16 into unpadded [128][32] LDS tiles
// (DMA writes lane i at base + i*16B -> rows packed 4 lanes/row).
// M,N multiples of 128; K multiple of 32; lda/ldw elems, rows 16B-aligned.
// ---------------------------------------------------------------------------
template<typename TC, int RELU>
__global__ __launch_bounds__(256)
void gemm_bf(const u16* __restrict__ A, const u16* __restrict__ W,
             const float* __restrict__ bias, TC* __restrict__ C,
             int M, int N, int K, int lda, int ldw)
{
    __shared__ u16 As[128 * 32];
    __shared__ u16 Ws[128 * 32];

    const int m0 = blockIdx.y * 128;
    const int n0 = blockIdx.x * 128;
    const int tid  = threadIdx.x;
    const int lane = tid & 63;
    const int wv   = tid >> 6;
    const int fr   = lane & 15;
    const int q8   = (lane >> 4) * 8;
    const int mb   = (wv >> 1) * 64;
    const int nb   = (wv & 1) * 64;

    const int r16 = lane >> 2;          // 0..15 (staging row within 16-row group)
    const int c8  = (lane & 3) * 8;     // 0,8,16,24 (k sub-offset)

    f32x4 acc[4][4];
#pragma unroll
    for (int i = 0; i < 4; i++)
#pragma unroll
        for (int j = 0; j < 4; j++) acc[i][j] = (f32x4){0.f, 0.f, 0.f, 0.f};

    for (int k0 = 0; k0 < K; k0 += 32) {
        __syncthreads();
#pragma unroll
        for (int j = 0; j < 2; j++) {
            int rowA = m0 + wv * 32 + j * 16 + r16;
            int rowW = n0 + wv * 32 + j * 16 + r16;
            gload16(A + (size_t)rowA * lda + k0 + c8, &As[(wv * 32 + j * 16) * 32]);
            gload16(W + (size_t)rowW * ldw + k0 + c8, &Ws[(wv * 32 + j * 16) * 32]);
        }
        __syncthreads();

        short8 af[4], bf[4];
#pragma unroll
        for (int i = 0; i < 4; i++) af[i] = *(const short8*)&As[(mb + i * 16 + fr) * 32 + q8];
#pragma unroll
        for (int j = 0; j < 4; j++) bf[j] = *(const short8*)&Ws[(nb + j * 16 + fr) * 32 + q8];
#pragma unroll
        for (int i = 0; i < 4; i++)
#pragma unroll
            for (int j = 0; j < 4; j++)
                acc[i][j] = __builtin_amdgcn_mfma_f32_16x16x32_bf16(af[i], bf[j], acc[i][j], 0, 0, 0);
    }

#pragma unroll
    for (int i = 0; i < 4; i++) {
#pragma unroll
        for (int j = 0; j < 4; j++) {
            int gn = n0 + nb + j * 16 + fr;
            float bv = bias ? bias[gn] : 0.f;
#pragma unroll
            for (int r = 0; r < 4; r++) {
                int gm = m0 + mb + i * 16 + (lane >> 4) * 4 + r;
                float v = acc[i][j][r] + bv;
                if (RELU) v = fmaxf(v, 0.f);
                stv(&C[(size_t)gm * N + gn], v);
            }
        }
    }
}

// M = W3b @ W2 (256 x 64) f32+bf16; sb[d] = row-sum of W3b.
__global__ void prep_M(const float* __restrict__ W3, const float* __restrict__ W2,
                       u16* __restrict__ Mb, float* __restrict__ sb)
{
    int d = blockIdx.x, a = threadIdx.x;
    float s = 0.f;
    for (int j = 0; j < 256; j++)
        s += W3[d * 512 + 256 + j] * W2[j * 64 + a];
    Mb[d * 64 + a] = f2bu(s);
    if (a == 0) {
        float t = 0.f;
        for (int j = 0; j < 256; j++) t += W3[d * 512 + 256 + j];
        sb[d] = t;
    }
}

// ---------------------------------------------------------------------------
// Per-batch counting sort of edges by column. One block per batch, 512 thr.
// v2: emits flattened per-slot records edat = {(e<<16)|row, norm} so the
// gather kernel has NO pointer chase (norm computed here from LDS counts).
// ---------------------------------------------------------------------------
__global__ __launch_bounds__(512)
void sort_edges(const int* __restrict__ ecol, const int* __restrict__ erow,
                float* __restrict__ deg, int* __restrict__ node_off,
                uint2* __restrict__ edat)
{
    const int b = blockIdx.x;
    const int t = threadIdx.x;
    const int base = b * EE;
    __shared__ int cnt[512];
    __shared__ int tmp[512];
    __shared__ int off2[512];

    cnt[t] = 0;
    __syncthreads();
    for (int e = t; e < EE; e += 512) atomicAdd(&cnt[ecol[base + e]], 1);
    __syncthreads();

    int v = cnt[t];
    deg[b * NN + t] = (float)(v + 1);
    tmp[t] = v;
    __syncthreads();
    for (int s = 1; s < 512; s <<= 1) {
        int y = (t >= s) ? tmp[t - s] : 0;
        __syncthreads();
        tmp[t] += y;
        __syncthreads();
    }
    int excl = tmp[t] - v;
    node_off[b * NN + t] = excl;
    off2[t] = excl;
    __syncthreads();
    for (int e = t; e < EE; e += 512) {
        int c = ecol[base + e];
        int r = erow[base + e];
        int pos = atomicAdd(&off2[c], 1);
        float nrm = rsqrtf((float)((cnt[r] + 1) * (cnt[c] + 1)));
        edat[base + pos] = make_uint2(((unsigned)e << 16) | (unsigned)r,
                                      __float_as_uint(nrm));
    }
}

// ---------------------------------------------------------------------------
// Gather aggregation v2 (no atomics, no pointer chase): one block per node.
// ---------------------------------------------------------------------------
__global__ __launch_bounds__(256)
void edge_gather(const uint2* __restrict__ edat, const int* __restrict__ node_off,
                 const float* __restrict__ y1, const float* __restrict__ eattr,
                 float* __restrict__ agg1, u16* __restrict__ eaggb)
{
    const int j = blockIdx.x;
    const int b = j >> 9;
    const int cc = j & 511;
    const int tid  = threadIdx.x;
    const int wv   = tid >> 6;
    const int lane = tid & 63;
    const int start = node_off[j];
    const int end   = (cc == 511) ? EE : node_off[j + 1];

    f32x4 acc = (f32x4){0.f, 0.f, 0.f, 0.f};
    float acce = 0.f;
    for (int i = start + wv; i < end; i += 4) {
        uint2 ed = edat[(size_t)b * EE + i];
        float nw = __uint_as_float(ed.y);
        int r = (int)(ed.x & 0xffffu);
        int e = (int)(ed.x >> 16);
        f32x4 yv = *(const f32x4*)&y1[((size_t)(b * NN + r)) * 256 + lane * 4];
        acc += nw * yv;
        acce += nw * eattr[((size_t)(b * EE + e)) * 64 + lane];
    }

    __shared__ f32x4 redA[4][64];
    __shared__ float redB[4][64];
    redA[wv][lane] = acc;
    redB[wv][lane] = acce;
    __syncthreads();
    if (tid < 64) {
        f32x4 s = redA[0][tid];
        float se = redB[0][tid];
#pragma unroll
        for (int w = 1; w < 4; w++) { s += redA[w][tid]; se += redB[w][tid]; }
        *(f32x4*)&agg1[(size_t)j * 256 + tid * 4] = s;
        eaggb[(size_t)j * 64 + tid] = f2bu(se);
    }
}

// h = tanh((agg1 + aggM + (y1+sb)/deg)/deg + bias) * mask -> aggM in place
__global__ void gcn_finalize(const float* __restrict__ agg1, float* __restrict__ aggM,
                             const float* __restrict__ y1, const float* __restrict__ sb,
                             const float* __restrict__ deg, const float* __restrict__ gcn_bias,
                             const int* __restrict__ lengths)
{
    int idx4 = blockIdx.x * 256 + threadIdx.x;       // group-of-4 index
    int j  = idx4 >> 6;
    int d4 = (idx4 & 63) * 4;
    size_t base = (size_t)j * 256 + d4;
    float dg = deg[j];
    float inv = 1.f / dg;
    f32x4 a1 = *(const f32x4*)&agg1[base];
    f32x4 aM = *(const f32x4*)&aggM[base];
    f32x4 yv = *(const f32x4*)&y1[base];
    f32x4 sv = *(const f32x4*)&sb[d4];
    f32x4 gb = *(const f32x4*)&gcn_bias[d4];
    int b = j >> 9, p = j & 511;
    bool live = (p < lengths[b]);
    f32x4 o;
#pragma unroll
    for (int k = 0; k < 4; k++) {
        float a = (a1[k] + aM[k] + (yv[k] + sv[k]) * inv) * inv;
        o[k] = live ? tanhf(a + gb[k]) : 0.f;
    }
    *(f32x4*)&aggM[base] = o;
}

// bn_stats v3: per-block partials, ZERO atomics (the old version ended in
// 512 same-address atomicAdds per stat element -> ~50us serialization tail
// at the coherence point; VALUBusy was 0.9%).
__global__ void bn_stats(const float* __restrict__ X, float* __restrict__ psum,
                         float* __restrict__ psumsq, int R)
{
    int wv = threadIdx.x >> 6, lane = threadIdx.x & 63;
    f32x4 s = (f32x4){0.f, 0.f, 0.f, 0.f};
    f32x4 q = (f32x4){0.f, 0.f, 0.f, 0.f};
    for (int r = blockIdx.x * 4 + wv; r < R; r += gridDim.x * 4) {
        f32x4 v = *(const f32x4*)&X[(size_t)r * DD + lane * 4];
        s += v; q += v * v;
    }
    __shared__ f32x4 rs[4][64], rq[4][64];
    rs[wv][lane] = s; rq[wv][lane] = q;
    __syncthreads();
    if (threadIdx.x < 64) {
        f32x4 ts = rs[0][lane], tq = rq[0][lane];
#pragma unroll
        for (int w = 1; w < 4; w++) { ts += rs[w][lane]; tq += rq[w][lane]; }
        *(f32x4*)&psum[blockIdx.x * DD + lane * 4]   = ts;
        *(f32x4*)&psumsq[blockIdx.x * DD + lane * 4] = tq;
    }
}

// fold 512 partial vectors -> sums/sumsq. 32 blocks: (chunk 0..15) x
// (sums, sumsq); 16 atomics/address worst case (~1.6us, bounded contention).
__global__ void bn_reduce(const float* __restrict__ psum, const float* __restrict__ psumsq,
                          float* __restrict__ sums, float* __restrict__ sumsq)
{
    int arr = blockIdx.x & 1;
    int chunk = blockIdx.x >> 1;     // 0..15, 32 partials each
    int d = threadIdx.x;
    const float* src = arr ? psumsq : psum;
    float acc = 0.f;
    int i0 = chunk * 32;
    for (int i = i0; i < i0 + 32; i++) acc += src[i * DD + d];
    atomicAdd(arr ? &sumsq[d] : &sums[d], acc);
}

// X normalized in place; optional bf16 duplicate. f32x4 / 4 per thread.
__global__ void bn_apply(float* __restrict__ X, const float* __restrict__ sums,
                         const float* __restrict__ sumsq, const float* __restrict__ g,
                         const float* __restrict__ bt, int R, u16* __restrict__ dup)
{
    int idx4 = blockIdx.x * 256 + threadIdx.x;
    int d4 = (idx4 & 63) * 4;
    size_t base = (size_t)idx4 * 4;
    float invR = 1.f / (float)R;
    f32x4 sm = *(const f32x4*)&sums[d4];
    f32x4 sq = *(const f32x4*)&sumsq[d4];
    f32x4 gv = *(const f32x4*)&g[d4];
    f32x4 bv = *(const f32x4*)&bt[d4];
    f32x4 x  = *(const f32x4*)&X[base];
    f32x4 o;
#pragma unroll
    for (int k = 0; k < 4; k++) {
        float m   = sm[k] * invR;
        float var = sq[k] * invR - m * m;
        o[k] = (x[k] - m) * rsqrtf(fmaxf(var, 0.f) + EPSF) * gv[k] + bv[k];
    }
    *(f32x4*)&X[base] = o;
    if (dup) st4b(&dup[base], o);
}

// ---------------------------------------------------------------------------
// MFMA flash attention. v6: 512-thread blocks, 8 waves, 128 q-rows per
// block; grid 1024, qp = bid>>8 XCD-coherent. Ps is WAVE-LOCAL, PV in two
// 64-col halves over [128][68] Ps: LDS 52 KB -> 3 blocks/CU.
// ---------------------------------------------------------------------------
__global__ __launch_bounds__(512, 2)
void attn_mfma(const bf16* __restrict__ qkv, u16* __restrict__ out)
{
    const int bid = blockIdx.x;
    const int qp = bid >> 8;        // 0..3 (slow bits -> XCD-coherent (b,h))
    const int pr = bid & 255;
    const int h  = pr & 3;
    const int b  = pr >> 2;

    const int tid  = threadIdx.x;
    const int lane = tid & 63;
    const int wv   = tid >> 6;      // 0..7
    const int fr   = lane & 15;
    const int quad = lane >> 4;
    const int q8   = quad * 8;

    __shared__ u16 Ks[128][72];
    __shared__ u16 Vts[64][136];
    __shared__ u16 Ps[128][68];

    const u16* qb = (const u16*)qkv;
    const size_t bb = (size_t)(b * NN);
    const float CE = 0.125f * 1.44269504f;   // softmax scale folded into exp2

    // Q fragments in registers: wave wv owns q-rows qp*128 + wv*16 + fr.
    short8 aq[2];
#pragma unroll
    for (int ks = 0; ks < 2; ks++)
        aq[ks] = *(const short8*)(qb + (bb + qp * 128 + wv * 16 + fr) * 768
                                  + h * 64 + ks * 32 + q8);

    f32x4 O[4];
    float m_i[4], l_i[4];
#pragma unroll
    for (int t = 0; t < 4; t++) {
        O[t] = (f32x4){0.f, 0.f, 0.f, 0.f};
        m_i[t] = -1e30f; l_i[t] = 0.f;
    }

    for (int c = 0; c < 4; c++) {
        __syncthreads();            // previous chunk's LDS reads complete
#pragma unroll
        for (int i = 0; i < 2; i++) {
            int idx = i * 512 + tid;
            int r = idx >> 3, seg = idx & 7;
            uint4 u = *((const uint4*)(qb + (bb + c * 128 + r) * 768 + 256 + h * 64) + seg);
            *(uint4*)&Ks[r][seg * 8] = u;
            uint4 v = *((const uint4*)(qb + (bb + c * 128 + r) * 768 + 512 + h * 64) + seg);
            // V^T store, 16B-granular XOR swizzle (seg == d>>3 for all 8 elems)
            u16* dst = &Vts[seg * 8][r ^ (seg << 3)];
            dst[0*136] = (u16)(v.x & 0xffff); dst[1*136] = (u16)(v.x >> 16);
            dst[2*136] = (u16)(v.y & 0xffff); dst[3*136] = (u16)(v.y >> 16);
            dst[4*136] = (u16)(v.z & 0xffff); dst[5*136] = (u16)(v.z >> 16);
            dst[6*136] = (u16)(v.w & 0xffff); dst[7*136] = (u16)(v.w >> 16);
        }
        __syncthreads();

        f32x4 S[8];
#pragma unroll
        for (int t = 0; t < 8; t++) S[t] = (f32x4){0.f, 0.f, 0.f, 0.f};
        __builtin_amdgcn_s_setprio(1);
#pragma unroll
        for (int ks = 0; ks < 2; ks++) {
#pragma unroll
            for (int t = 0; t < 8; t++) {
                short8 bk = *(const short8*)&Ks[t * 16 + fr][ks * 32 + q8];
                S[t] = __builtin_amdgcn_mfma_f32_16x16x32_bf16(aq[ks], bk, S[t], 0, 0, 0);
            }
        }
        __builtin_amdgcn_s_setprio(0);

        float mc[4];
#pragma unroll
        for (int r = 0; r < 4; r++) {
            float mm = -1e30f;
#pragma unroll
            for (int t = 0; t < 8; t++) mm = fmaxf(mm, S[t][r]);
            mc[r] = mm;
        }
#pragma unroll
        for (int msk = 1; msk < 16; msk <<= 1)
#pragma unroll
            for (int r = 0; r < 4; r++) mc[r] = fmaxf(mc[r], __shfl_xor(mc[r], msk));

        float alpha[4], ls[4];
#pragma unroll
        for (int r = 0; r < 4; r++) {
            float mn = fmaxf(m_i[r], mc[r]);
            alpha[r] = __builtin_amdgcn_exp2f((m_i[r] - mn) * CE);
            m_i[r] = mn;
            ls[r] = 0.f;
        }
        // rescale O before accumulating this chunk's PV
#pragma unroll
        for (int t = 0; t < 4; t++)
#pragma unroll
            for (int r = 0; r < 4; r++) O[t][r] *= alpha[r];

        // two 64-col halves: write P (wave-local), then PV on that half
#pragma unroll
        for (int hf = 0; hf < 2; hf++) {
#pragma unroll
            for (int tl = 0; tl < 4; tl++) {
                int t = hf * 4 + tl;
#pragma unroll
                for (int r = 0; r < 4; r++) {
                    float p = __builtin_amdgcn_exp2f((S[t][r] - m_i[r]) * CE);
                    Ps[wv * 16 + quad * 4 + r][tl * 16 + fr] = f2bu(p);
                    ls[r] += p;
                }
            }
            __builtin_amdgcn_s_setprio(1);
#pragma unroll
            for (int ks = 0; ks < 2; ks++) {
                short8 ap = *(const short8*)&Ps[wv * 16 + fr][ks * 32 + q8];
                int g = hf * 2 + ks;
#pragma unroll
                for (int t = 0; t < 4; t++) {
                    short8 bv = *(const short8*)&Vts[t * 16 + fr]
                                    [(g * 32 + q8) ^ ((t * 2 + (fr >> 3)) << 3)];
                    O[t] = __builtin_amdgcn_mfma_f32_16x16x32_bf16(ap, bv, O[t], 0, 0, 0);
                }
            }
            __builtin_amdgcn_s_setprio(0);
        }

#pragma unroll
        for (int msk = 1; msk < 16; msk <<= 1)
#pragma unroll
            for (int r = 0; r < 4; r++) ls[r] += __shfl_xor(ls[r], msk);
#pragma unroll
        for (int r = 0; r < 4; r++) l_i[r] = l_i[r] * alpha[r] + ls[r];
    }

#pragma unroll
    for (int t = 0; t < 4; t++)
#pragma unroll
        for (int r = 0; r < 4; r++) {
            int q = qp * 128 + wv * 16 + quad * 4 + r;
            out[(bb + q) * 256 + h * 64 + t * 16 + fr] = f2bu(O[t][r] / l_i[r]);
        }
}

// out = LN(X + Y); optional bf16 duplicate. One wave per row, zero barriers.
__global__ void add_ln_kernel(const float* __restrict__ X, const float* __restrict__ Y,
                              const float* __restrict__ g, const float* __restrict__ bt,
                              float* __restrict__ out, u16* __restrict__ dup)
{
    int wv = threadIdx.x >> 6, lane = threadIdx.x & 63;
    int row = blockIdx.x * 4 + wv;
    size_t base = (size_t)row * DD + lane * 4;
    f32x4 v = *(const f32x4*)&X[base] + *(const f32x4*)&Y[base];
    float s = v[0] + v[1] + v[2] + v[3];
#pragma unroll
    for (int m = 1; m < 64; m <<= 1) s += __shfl_xor(s, m);
    float mean = s * (1.f / DD);
    f32x4 d;
#pragma unroll
    for (int k = 0; k < 4; k++) d[k] = v[k] - mean;
    float q = d[0]*d[0] + d[1]*d[1] + d[2]*d[2] + d[3]*d[3];
#pragma unroll
    for (int m = 1; m < 64; m <<= 1) q += __shfl_xor(q, m);
    float inv = rsqrtf(q * (1.f / DD) + EPSF);
    f32x4 gv = *(const f32x4*)&g[lane * 4];
    f32x4 bv = *(const f32x4*)&bt[lane * 4];
    f32x4 o;
#pragma unroll
    for (int k = 0; k < 4; k++) o[k] = d[k] * inv * gv[k] + bv[k];
    *(f32x4*)&out[base] = o;
    if (dup) st4b(&dup[base], o);
}

__global__ void pool_kernel(const float* __restrict__ enc, const int* __restrict__ lengths,
                            float* __restrict__ poolbuf)
{
    int b = blockIdx.x;
    int wv = threadIdx.x >> 6, lane = threadIdx.x & 63;
    int L = lengths[b];
    if (L < 1) L = 1;
    f32x4 s  = (f32x4){0.f, 0.f, 0.f, 0.f};
    f32x4 mx = (f32x4){-1e30f, -1e30f, -1e30f, -1e30f};
    for (int n = wv; n < NN; n += 4) {
        f32x4 v = *(const f32x4*)&enc[((size_t)b * NN + n) * DD + lane * 4];
        s += v;
        if (n < L) {
#pragma unroll
            for (int k = 0; k < 4; k++) mx[k] = fmaxf(mx[k], v[k]);
        }
    }
    __shared__ f32x4 rs[4][64], rm[4][64];
    rs[wv][lane] = s; rm[wv][lane] = mx;
    __syncthreads();
    if (threadIdx.x < 64) {
        f32x4 ts = rs[0][lane], tm = rm[0][lane];
#pragma unroll
        for (int w = 1; w < 4; w++) {
            ts += rs[w][lane];
#pragma unroll
            for (int k = 0; k < 4; k++) tm[k] = fmaxf(tm[k], rm[w][lane][k]);
        }
        float invL = 1.f / (float)L;
#pragma unroll
        for (int k = 0; k < 4; k++) {
            poolbuf[b * 512 + lane * 4 + k]       = tm[k];
            poolbuf[b * 512 + 256 + lane * 4 + k] = ts[k] * invL;
        }
    }
}

__global__ void head_kernel(const float* __restrict__ poolbuf, const float* __restrict__ lin_w,
                            const float* __restrict__ lin_b, const float* __restrict__ g,
                            const float* __restrict__ bt, float* __restrict__ out)
{
    int b = threadIdx.x;
    float r0 = lin_b[0], r1 = lin_b[1];
    for (int k = 0; k < 512; k++) {
        float p = poolbuf[b * 512 + k];
        r0 += p * lin_w[k];
        r1 += p * lin_w[512 + k];
    }
    __shared__ float s0[64], s1[64], mstat[4];
    s0[b] = r0; s1[b] = r1; __syncthreads();
    if (b == 0) {
        float a0 = 0, a1 = 0, q0 = 0, q1 = 0;
        for (int i = 0; i < 64; i++) { a0 += s0[i]; a1 += s1[i]; }
        a0 *= (1.f / 64.f); a1 *= (1.f / 64.f);
        for (int i = 0; i < 64; i++) {
            float d0 = s0[i] - a0, d1 = s1[i] - a1;
            q0 += d0 * d0; q1 += d1 * d1;
        }
        mstat[0] = a0; mstat[1] = a1; mstat[2] = q0 * (1.f / 64.f); mstat[3] = q1 * (1.f / 64.f);
    }
    __syncthreads();
    float z0 = (r0 - mstat[0]) * rsqrtf(mstat[2] + EPSF) * g[0] + bt[0];
    float z1 = (r1 - mstat[1]) * rsqrtf(mstat[3] + EPSF) * g[1] + bt[1];
    float mx = fmaxf(z0, z1);
    float e0 = __expf(z0 - mx), e1 = __expf(z1 - mx);
    float inv = 1.f / (e0 + e1);
    out[b * 2 + 0] = e0 * inv;
    out[b * 2 + 1] = e1 * inv;
}

extern "C" void kernel_launch(void* const* d_in, const int* in_sizes, int n_in,
                              void* d_out, int out_size, void* d_ws, size_t ws_size,
                              hipStream_t stream)
{
    (void)in_sizes; (void)n_in; (void)out_size; (void)ws_size;
    const float* x          = (const float*)d_in[0];
    const float* edge_attr  = (const float*)d_in[1];
    const float* W1         = (const float*)d_in[5];
    const float* W2         = (const float*)d_in[6];
    const float* W3         = (const float*)d_in[7];
    const float* b3         = (const float*)d_in[8];
    const float* gcn_bias   = (const float*)d_in[9];
    const float* bn1_g      = (const float*)d_in[10];
    const float* bn1_b      = (const float*)d_in[11];
    const float* in_proj_w  = (const float*)d_in[12];
    const float* in_proj_b  = (const float*)d_in[13];
    const float* out_proj_w = (const float*)d_in[14];
    const float* out_proj_b = (const float*)d_in[15];
    const float* ln1_g      = (const float*)d_in[16];
    const float* ln1_b      = (const float*)d_in[17];
    const float* lin1_w     = (const float*)d_in[18];
    const float* lin1_b     = (const float*)d_in[19];
    const float* lin2_w     = (const float*)d_in[20];
    const float* lin2_b     = (const float*)d_in[21];
    const float* ln2_g      = (const float*)d_in[22];
    const float* ln2_b      = (const float*)d_in[23];
    const float* bn2_g      = (const float*)d_in[24];
    const float* bn2_b      = (const float*)d_in[25];
    const float* lin_w      = (const float*)d_in[26];
    const float* lin_b      = (const float*)d_in[27];
    const float* bn3_g      = (const float*)d_in[28];
    const float* bn3_b      = (const float*)d_in[29];

    // ---- Workspace layout (~187 MB) ----
    char* p = (char*)d_ws;
    u16*   big   = (u16*)p;   p += (size_t)BN_TOT * 1024 * 2;   // 64 MiB: [xb|(unused)|eaggb] -> qkv -> ffa
    float* bufA  = (float*)p; p += (size_t)BN_TOT * 256 * 4;    // aggM/h -> ffb
    float* bufB  = (float*)p; p += (size_t)BN_TOT * 256 * 4;    // y1 -> attnp -> h2
    float* bufC  = (float*)p; p += (size_t)BN_TOT * 256 * 4;    // agg1 -> h1
    u16*   bufP  = (u16*)p;   p += (size_t)BN_TOT * 256 * 2;    // 16.8 MB: hb -> attnoutb -> h1b
    float* deg   = (float*)p; p += (size_t)BN_TOT * 4;
    u16*   Mb    = (u16*)p;   p += 256 * 64 * 2;
    float* sb    = (float*)p; p += 1024;
    float* stats = (float*)p; p += 4 * 256 * 4;
    float* psum  = (float*)p; p += 512 * 256 * 4;               // bn partials
    float* psumsq= (float*)p; p += 512 * 256 * 4;
    float* poolbuf=(float*)p; p += 64 * 512 * 4;
    int*   flags = (int*)p;   p += 256;
    int*   erc   = (int*)p;   p += BE_TOT * 4;
    int*   ecc   = (int*)p;   p += BE_TOT * 4;
    int*   lenc  = (int*)p;   p += 256;
    uint2* edat  = (uint2*)p; p += (size_t)BE_TOT * 8;
    int*   noff  = (int*)p;   p += BN_TOT * 4;
    u16*   W13b  = (u16*)p;   p += 256 * 320 * 2;
    u16*   ipwb  = (u16*)p;   p += 768 * 256 * 2;
    u16*   opwb  = (u16*)p;   p += 256 * 256 * 2;
    u16*   l1wb  = (u16*)p;   p += 1024 * 256 * 2;
    u16*   l2wb  = (u16*)p;   p += 256 * 1024 * 2;

    // bf16 temporaries inside big (all dead before qkv is written at in_proj)
    u16* xb    = big;                              // 32768 x 320
    u16* eaggb = big + (size_t)BN_TOT * (320+256); // 32768 x 64
    bf16* qkv  = (bf16*)big;
    bf16* ffa  = (bf16*)big;

    float* y1      = bufB;
    float* agg1    = bufC;
    float* aggM    = bufA;    // becomes h in finalize
    float* h       = bufA;
    u16*   hb      = bufP;
    u16*   attnoutb= bufP;    // hb dead after in_proj GEMM
    float* attnp   = bufB;    // y1 dead after finalize
    float* h1      = bufC;    // agg1 dead after finalize
    u16*   h1b     = bufP;    // attnoutb dead after out_proj GEMM
    float* ffb     = bufA;    // h dead after add_ln #1
    float* h2      = bufB;    // attnp dead after add_ln #1

    hipMemsetAsync(stats, 0, 4 * 256 * 4, stream);

    detect_kernel<<<1, 1, 0, stream>>>((const int*)d_in[4], flags);
    conv_i2<<<(2 * BE_TOT + 255) / 256, 256, 0, stream>>>(d_in[2], erc, d_in[3], ecc,
                                                          BE_TOT, flags);
    conv_i<<<1, 64, 0, stream>>>(d_in[4], lenc, BB, flags);

    // input conversion + fused weight conversions
    conv_pad<<<(BN_TOT * 80 + 255) / 256, 256, 0, stream>>>(x, xb, BN_TOT, FINK, 320);
    conv_w4<<<768, 256, 0, stream>>>(in_proj_w, ipwb, out_proj_w, opwb,
                                     lin1_w, l1wb, lin2_w, l2wb);

    prep_W13<<<256, 320, 0, stream>>>(W3, W1, W13b);
    prep_M<<<256, 64, 0, stream>>>(W3, W2, Mb, sb);
    sort_edges<<<BB, 512, 0, stream>>>(ecc, erc, deg, noff, edat);

    // y1 = x @ (W3a@W1).T + b3  (xs GEMM folded into the weight)
    gemm_bf<float, 0><<<dim3(2, 256), 256, 0, stream>>>(
        xb, W13b, b3, y1, BN_TOT, 256, 320, 320, 320);

    edge_gather<<<BN_TOT, 256, 0, stream>>>(edat, noff, y1, edge_attr, agg1, eaggb);
    gemm_bf<float, 0><<<dim3(2, 256), 256, 0, stream>>>(
        eaggb, Mb, nullptr, aggM, BN_TOT, 256, 64, 64, 64);

    gcn_finalize<<<BN_TOT / 4, 256, 0, stream>>>(agg1, aggM, y1, sb, deg, gcn_bias, lenc);

    bn_stats<<<512, 256, 0, stream>>>(h, psum, psumsq, BN_TOT);
    bn_reduce<<<32, 256, 0, stream>>>(psum, psumsq, stats, stats + 256);
    bn_apply<<<BN_TOT / 4, 256, 0, stream>>>(h, stats, stats + 256, bn1_g, bn1_b, BN_TOT, hb);

    gemm_bf<bf16, 0><<<dim3(6, 256), 256, 0, stream>>>(
        hb, ipwb, in_proj_b, qkv, BN_TOT, 768, 256, 256, 256);

    attn_mfma<<<BB * 4 * 4, 512, 0, stream>>>(qkv, attnoutb);

    gemm_bf<float, 0><<<dim3(2, 256), 256, 0, stream>>>(
        attnoutb, opwb, out_proj_b, attnp, BN_TOT, 256, 256, 256, 256);

    add_ln_kernel<<<BN_TOT / 4, 256, 0, stream>>>(h, attnp, ln1_g, ln1_b, h1, h1b);

    gemm_bf<bf16, 1><<<dim3(8, 256), 256, 0, stream>>>(
        h1b, l1wb, lin1_b, ffa, BN_TOT, 1024, 256, 256, 256);
    gemm_bf<float, 0><<<dim3(2, 256), 256, 0, stream>>>(
        (const u16*)ffa, l2wb, lin2_b, ffb, BN_TOT, 256, 1024, 1024, 1024);

    add_ln_kernel<<<BN_TOT / 4, 256, 0, stream>>>(h1, ffb, ln2_g, ln2_b, h2, nullptr);

    bn_stats<<<512, 256, 0, stream>>>(h2, psum, psumsq, BN_TOT);
    bn_reduce<<<32, 256, 0, stream>>>(psum, psumsq, stats + 512, stats + 768);
    bn_apply<<<BN_TOT / 4, 256, 0, stream>>>(h2, stats + 512, stats + 768, bn2_g, bn2_b, BN_TOT, nullptr);

    pool_kernel<<<64, 256, 0, stream>>>(h2, lenc, poolbuf);
    head_kernel<<<1, 64, 0, stream>>>(poolbuf, lin_w, lin_b, bn3_g, bn3_b, (float*)d_out);
}

// Round 11
// 575.108 us; speedup vs baseline: 1.2155x; 1.0320x over previous
//
#include <hip/hip_runtime.h>
#include <hip/hip_bf16.h>

// Shapes
#define BB   64
#define NN   512
#define EE   2048
#define FINK 300
#define DD   256
#define BN_TOT (BB*NN)    // 32768
#define BE_TOT (BB*EE)    // 131072
#define EPSF 1e-5f

using bf16 = __hip_bfloat16;
typedef unsigned short u16;
typedef __attribute__((ext_vector_type(8))) short short8;
typedef __attribute__((ext_vector_type(4))) float f32x4;
typedef __attribute__((ext_vector_type(4))) unsigned short u16x4;

__device__ __forceinline__ float tf(float x) { return x; }
__device__ __forceinline__ float tf(bf16 x)  { return __bfloat162float(x); }
__device__ __forceinline__ void  stv(float* p, float v) { *p = v; }
__device__ __forceinline__ void  stv(bf16*  p, float v) { *p = __float2bfloat16(v); }

__device__ __forceinline__ u16 f2bu(float f) {
    bf16 b = __float2bfloat16(f);
    return *(u16*)&b;
}
// f32x4 -> 4x bf16 stored as one 8B write
__device__ __forceinline__ void st4b(u16* p, f32x4 v)
{
    u16x4 o;
    o[0] = f2bu(v[0]); o[1] = f2bu(v[1]); o[2] = f2bu(v[2]); o[3] = f2bu(v[3]);
    *(u16x4*)p = o;
}

// Direct global->LDS DMA, 16B per lane. LDS dst = wave-uniform base + lane*16.
__device__ __forceinline__ void gload16(const void* g, void* l)
{
    __builtin_amdgcn_global_load_lds((const __attribute__((address_space(1))) void*)g,
                                     (__attribute__((address_space(3))) void*)l, 16, 0, 0);
}

// Int dtype probe: lengths[1] as int32 is in [256,512] iff int32 storage;
// it is the zero hi-word of lengths[0] iff int64 (LE).
__global__ void detect_kernel(const int* __restrict__ lengths, int* __restrict__ flags)
{
    flags[1] = (lengths[1] == 0) ? 1 : 0;
}

__global__ void conv_i(const void* __restrict__ src, int* __restrict__ dst, int n,
                       const int* __restrict__ flags)
{
    int i = blockIdx.x * 256 + threadIdx.x;
    if (i >= n) return;
    const int* s = (const int*)src;
    dst[i] = s[flags[1] ? (i << 1) : i];
}

// both edge-index conversions in one launch
__global__ void conv_i2(const void* __restrict__ src1, int* __restrict__ dst1,
                        const void* __restrict__ src2, int* __restrict__ dst2,
                        int n, const int* __restrict__ flags)
{
    int i = blockIdx.x * 256 + threadIdx.x;
    int wide = flags[1];
    if (i < n) {
        dst1[i] = ((const int*)src1)[wide ? (i << 1) : i];
    } else if (i < 2 * n) {
        int k = i - n;
        dst2[k] = ((const int*)src2)[wide ? (k << 1) : k];
    }
}

// f32 (rows x sk) -> bf16 (rows x dk) zero-padded, 4 cols/thread.
__global__ void conv_pad(const float* __restrict__ src, u16* __restrict__ dst, int rows,
                         int sk, int dk)
{
    int dk4 = dk >> 2;
    int i = blockIdx.x * 256 + threadIdx.x;
    if (i >= rows * dk4) return;
    int r = i / dk4, c4 = (i - r * dk4) * 4;
    if (c4 < sk) {
        f32x4 v = *(const f32x4*)&src[(size_t)r * sk + c4];
        st4b(&dst[(size_t)r * dk + c4], v);
    } else {
        *(u16x4*)&dst[(size_t)r * dk + c4] = (u16x4){0, 0, 0, 0};
    }
}

// all four plain f32->bf16 weight conversions in one launch (quad ranges:
// ipw 49152, opw 16384, l1w 65536, l2w 65536 -> 196608 quads, 768 blocks)
__global__ void conv_w4(const float* __restrict__ s0, u16* __restrict__ d0,
                        const float* __restrict__ s1, u16* __restrict__ d1,
                        const float* __restrict__ s2, u16* __restrict__ d2,
                        const float* __restrict__ s3, u16* __restrict__ d3)
{
    int i = blockIdx.x * 256 + threadIdx.x;
    const float* s; u16* d; int off;
    if (i < 49152)       { s = s0; d = d0; off = i; }
    else if (i < 65536)  { s = s1; d = d1; off = i - 49152; }
    else if (i < 131072) { s = s2; d = d2; off = i - 65536; }
    else                 { s = s3; d = d3; off = i - 131072; }
    f32x4 v = *(const f32x4*)&s[(size_t)off * 4];
    st4b(&d[(size_t)off * 4], v);
}

// W13 = W3[:, :256] @ W1  (256 x 320 bf16, zero-padded cols 300..319).
// Folds the xs = x@W1.T GEMM into y1 = x@W13.T (+b3).
__global__ void prep_W13(const float* __restrict__ W3, const float* __restrict__ W1,
                         u16* __restrict__ W13b)
{
    int d = blockIdx.x;      // 0..255
    int f = threadIdx.x;     // 0..319
    float s = 0.f;
    if (f < FINK) {
        for (int j = 0; j < 256; j++)
            s += W3[d * 512 + j] * W1[j * FINK + f];
    }
    W13b[d * 320 + f] = f2bu(s);
}

// ---------------------------------------------------------------------------
// MFMA GEMM v2: C[m,n] = sum_k A[m,k]*W[n*ldw+k] (+bias,+relu)
// Tile 128x128, 4 waves, K-step 64 (BK=64: half the barriers of BK=32,
// 32 MFMA per barrier pair). LDS rows are 128B = exact 32-bank alias, so
// T2 XOR-swizzle applied BOTH sides (rule #21): global SOURCE col is
// pre-swizzled (linear LDS dest via global_load_lds), fragment reads XOR
// the same pattern -> 8 lanes on 8 distinct banks (2/bank = free).
// M,N multiples of 128; K multiple of 64; lda/ldw elems, rows 16B-aligned.
// ---------------------------------------------------------------------------
template<typename TC, int RELU>
__global__ __launch_bounds__(256)
void gemm_bf(const u16* __restrict__ A, const u16* __restrict__ W,
             const float* __restrict__ bias, TC* __restrict__ C,
             int M, int N, int K, int lda, int ldw)
{
    __shared__ u16 As[128 * 64];
    __shared__ u16 Ws[128 * 64];

    const int m0 = blockIdx.y * 128;
    const int n0 = blockIdx.x * 128;
    const int tid  = threadIdx.x;
    const int lane = tid & 63;
    const int wv   = tid >> 6;
    const int fr   = lane & 15;
    const int q8   = (lane >> 4) * 8;
    const int mb   = (wv >> 1) * 64;
    const int nb   = (wv & 1) * 64;

    const int r8  = lane >> 3;                 // 0..7 (staging row in 8-row group)
    const int csw = 8 * ((lane & 7) ^ r8);     // swizzled source col within BK=64
    const int frx = (fr & 7) << 3;             // read-side XOR (same involution)

    f32x4 acc[4][4];
#pragma unroll
    for (int i = 0; i < 4; i++)
#pragma unroll
        for (int j = 0; j < 4; j++) acc[i][j] = (f32x4){0.f, 0.f, 0.f, 0.f};

    for (int k0 = 0; k0 < K; k0 += 64) {
        __syncthreads();
#pragma unroll
        for (int j = 0; j < 4; j++) {
            int rowA = m0 + wv * 32 + j * 8 + r8;
            int rowW = n0 + wv * 32 + j * 8 + r8;
            gload16(A + (size_t)rowA * lda + k0 + csw, &As[(wv * 32 + j * 8) * 64]);
            gload16(W + (size_t)rowW * ldw + k0 + csw, &Ws[(wv * 32 + j * 8) * 64]);
        }
        __syncthreads();

#pragma unroll
        for (int ks = 0; ks < 2; ks++) {
            int rc = (ks * 32 + q8) ^ frx;
            short8 af[4], bf[4];
#pragma unroll
            for (int i = 0; i < 4; i++) af[i] = *(const short8*)&As[(mb + i * 16 + fr) * 64 + rc];
#pragma unroll
            for (int j = 0; j < 4; j++) bf[j] = *(const short8*)&Ws[(nb + j * 16 + fr) * 64 + rc];
#pragma unroll
            for (int i = 0; i < 4; i++)
#pragma unroll
                for (int j = 0; j < 4; j++)
                    acc[i][j] = __builtin_amdgcn_mfma_f32_16x16x32_bf16(af[i], bf[j], acc[i][j], 0, 0, 0);
        }
    }

#pragma unroll
    for (int i = 0; i < 4; i++) {
#pragma unroll
        for (int j = 0; j < 4; j++) {
            int gn = n0 + nb + j * 16 + fr;
            float bv = bias ? bias[gn] : 0.f;
#pragma unroll
            for (int r = 0; r < 4; r++) {
                int gm = m0 + mb + i * 16 + (lane >> 4) * 4 + r;
                float v = acc[i][j][r] + bv;
                if (RELU) v = fmaxf(v, 0.f);
                stv(&C[(size_t)gm * N + gn], v);
            }
        }
    }
}

// M = W3b @ W2 (256 x 64) f32+bf16; sb[d] = row-sum of W3b.
__global__ void prep_M(const float* __restrict__ W3, const float* __restrict__ W2,
                       u16* __restrict__ Mb, float* __restrict__ sb)
{
    int d = blockIdx.x, a = threadIdx.x;
    float s = 0.f;
    for (int j = 0; j < 256; j++)
        s += W3[d * 512 + 256 + j] * W2[j * 64 + a];
    Mb[d * 64 + a] = f2bu(s);
    if (a == 0) {
        float t = 0.f;
        for (int j = 0; j < 256; j++) t += W3[d * 512 + 256 + j];
        sb[d] = t;
    }
}

// ---------------------------------------------------------------------------
// Per-batch counting sort of edges by column. One block per batch, 512 thr.
// Emits flattened per-slot records edat = {(e<<16)|row, norm}.
// ---------------------------------------------------------------------------
__global__ __launch_bounds__(512)
void sort_edges(const int* __restrict__ ecol, const int* __restrict__ erow,
                float* __restrict__ deg, int* __restrict__ node_off,
                uint2* __restrict__ edat)
{
    const int b = blockIdx.x;
    const int t = threadIdx.x;
    const int base = b * EE;
    __shared__ int cnt[512];
    __shared__ int tmp[512];
    __shared__ int off2[512];

    cnt[t] = 0;
    __syncthreads();
    for (int e = t; e < EE; e += 512) atomicAdd(&cnt[ecol[base + e]], 1);
    __syncthreads();

    int v = cnt[t];
    deg[b * NN + t] = (float)(v + 1);
    tmp[t] = v;
    __syncthreads();
    for (int s = 1; s < 512; s <<= 1) {
        int y = (t >= s) ? tmp[t - s] : 0;
        __syncthreads();
        tmp[t] += y;
        __syncthreads();
    }
    int excl = tmp[t] - v;
    node_off[b * NN + t] = excl;
    off2[t] = excl;
    __syncthreads();
    for (int e = t; e < EE; e += 512) {
        int c = ecol[base + e];
        int r = erow[base + e];
        int pos = atomicAdd(&off2[c], 1);
        float nrm = rsqrtf((float)((cnt[r] + 1) * (cnt[c] + 1)));
        edat[base + pos] = make_uint2(((unsigned)e << 16) | (unsigned)r,
                                      __float_as_uint(nrm));
    }
}

// ---------------------------------------------------------------------------
// Gather aggregation (no atomics, no pointer chase): one block per node.
// ---------------------------------------------------------------------------
__global__ __launch_bounds__(256)
void edge_gather(const uint2* __restrict__ edat, const int* __restrict__ node_off,
                 const float* __restrict__ y1, const float* __restrict__ eattr,
                 float* __restrict__ agg1, u16* __restrict__ eaggb)
{
    const int j = blockIdx.x;
    const int b = j >> 9;
    const int cc = j & 511;
    const int tid  = threadIdx.x;
    const int wv   = tid >> 6;
    const int lane = tid & 63;
    const int start = node_off[j];
    const int end   = (cc == 511) ? EE : node_off[j + 1];

    f32x4 acc = (f32x4){0.f, 0.f, 0.f, 0.f};
    float acce = 0.f;
    for (int i = start + wv; i < end; i += 4) {
        uint2 ed = edat[(size_t)b * EE + i];
        float nw = __uint_as_float(ed.y);
        int r = (int)(ed.x & 0xffffu);
        int e = (int)(ed.x >> 16);
        f32x4 yv = *(const f32x4*)&y1[((size_t)(b * NN + r)) * 256 + lane * 4];
        acc += nw * yv;
        acce += nw * eattr[((size_t)(b * EE + e)) * 64 + lane];
    }

    __shared__ f32x4 redA[4][64];
    __shared__ float redB[4][64];
    redA[wv][lane] = acc;
    redB[wv][lane] = acce;
    __syncthreads();
    if (tid < 64) {
        f32x4 s = redA[0][tid];
        float se = redB[0][tid];
#pragma unroll
        for (int w = 1; w < 4; w++) { s += redA[w][tid]; se += redB[w][tid]; }
        *(f32x4*)&agg1[(size_t)j * 256 + tid * 4] = s;
        eaggb[(size_t)j * 64 + tid] = f2bu(se);
    }
}

// h = tanh((agg1 + aggM + (y1+sb)/deg)/deg + bias) * mask -> aggM in place
__global__ void gcn_finalize(const float* __restrict__ agg1, float* __restrict__ aggM,
                             const float* __restrict__ y1, const float* __restrict__ sb,
                             const float* __restrict__ deg, const float* __restrict__ gcn_bias,
                             const int* __restrict__ lengths)
{
    int idx4 = blockIdx.x * 256 + threadIdx.x;       // group-of-4 index
    int j  = idx4 >> 6;
    int d4 = (idx4 & 63) * 4;
    size_t base = (size_t)j * 256 + d4;
    float dg = deg[j];
    float inv = 1.f / dg;
    f32x4 a1 = *(const f32x4*)&agg1[base];
    f32x4 aM = *(const f32x4*)&aggM[base];
    f32x4 yv = *(const f32x4*)&y1[base];
    f32x4 sv = *(const f32x4*)&sb[d4];
    f32x4 gb = *(const f32x4*)&gcn_bias[d4];
    int b = j >> 9, p = j & 511;
    bool live = (p < lengths[b]);
    f32x4 o;
#pragma unroll
    for (int k = 0; k < 4; k++) {
        float a = (a1[k] + aM[k] + (yv[k] + sv[k]) * inv) * inv;
        o[k] = live ? tanhf(a + gb[k]) : 0.f;
    }
    *(f32x4*)&aggM[base] = o;
}

// bn_stats: per-block partials, ZERO atomics (512 same-address atomics was a
// ~50us serialization tail).
__global__ void bn_stats(const float* __restrict__ X, float* __restrict__ psum,
                         float* __restrict__ psumsq, int R)
{
    int wv = threadIdx.x >> 6, lane = threadIdx.x & 63;
    f32x4 s = (f32x4){0.f, 0.f, 0.f, 0.f};
    f32x4 q = (f32x4){0.f, 0.f, 0.f, 0.f};
    for (int r = blockIdx.x * 4 + wv; r < R; r += gridDim.x * 4) {
        f32x4 v = *(const f32x4*)&X[(size_t)r * DD + lane * 4];
        s += v; q += v * v;
    }
    __shared__ f32x4 rs[4][64], rq[4][64];
    rs[wv][lane] = s; rq[wv][lane] = q;
    __syncthreads();
    if (threadIdx.x < 64) {
        f32x4 ts = rs[0][lane], tq = rq[0][lane];
#pragma unroll
        for (int w = 1; w < 4; w++) { ts += rs[w][lane]; tq += rq[w][lane]; }
        *(f32x4*)&psum[blockIdx.x * DD + lane * 4]   = ts;
        *(f32x4*)&psumsq[blockIdx.x * DD + lane * 4] = tq;
    }
}

// fold 512 partial vectors -> sums/sumsq. 32 blocks; 16 atomics/address max.
__global__ void bn_reduce(const float* __restrict__ psum, const float* __restrict__ psumsq,
                          float* __restrict__ sums, float* __restrict__ sumsq)
{
    int arr = blockIdx.x & 1;
    int chunk = blockIdx.x >> 1;     // 0..15, 32 partials each
    int d = threadIdx.x;
    const float* src = arr ? psumsq : psum;
    float acc = 0.f;
    int i0 = chunk * 32;
    for (int i = i0; i < i0 + 32; i++) acc += src[i * DD + d];
    atomicAdd(arr ? &sumsq[d] : &sums[d], acc);
}

// X normalized in place; optional bf16 duplicate. f32x4 / 4 per thread.
__global__ void bn_apply(float* __restrict__ X, const float* __restrict__ sums,
                         const float* __restrict__ sumsq, const float* __restrict__ g,
                         const float* __restrict__ bt, int R, u16* __restrict__ dup)
{
    int idx4 = blockIdx.x * 256 + threadIdx.x;
    int d4 = (idx4 & 63) * 4;
    size_t base = (size_t)idx4 * 4;
    float invR = 1.f / (float)R;
    f32x4 sm = *(const f32x4*)&sums[d4];
    f32x4 sq = *(const f32x4*)&sumsq[d4];
    f32x4 gv = *(const f32x4*)&g[d4];
    f32x4 bv = *(const f32x4*)&bt[d4];
    f32x4 x  = *(const f32x4*)&X[base];
    f32x4 o;
#pragma unroll
    for (int k = 0; k < 4; k++) {
        float m   = sm[k] * invR;
        float var = sq[k] * invR - m * m;
        o[k] = (x[k] - m) * rsqrtf(fmaxf(var, 0.f) + EPSF) * gv[k] + bv[k];
    }
    *(f32x4*)&X[base] = o;
    if (dup) st4b(&dup[base], o);
}

// ---------------------------------------------------------------------------
// MFMA flash attention. v6: 512-thread blocks, 8 waves, 128 q-rows per
// block; grid 1024, qp = bid>>8 XCD-coherent. Ps is WAVE-LOCAL, PV in two
// 64-col halves over [128][68] Ps: LDS 52 KB.
// ---------------------------------------------------------------------------
__global__ __launch_bounds__(512, 2)
void attn_mfma(const bf16* __restrict__ qkv, u16* __restrict__ out)
{
    const int bid = blockIdx.x;
    const int qp = bid >> 8;        // 0..3 (slow bits -> XCD-coherent (b,h))
    const int pr = bid & 255;
    const int h  = pr & 3;
    const int b  = pr >> 2;

    const int tid  = threadIdx.x;
    const int lane = tid & 63;
    const int wv   = tid >> 6;      // 0..7
    const int fr   = lane & 15;
    const int quad = lane >> 4;
    const int q8   = quad * 8;

    __shared__ u16 Ks[128][72];
    __shared__ u16 Vts[64][136];
    __shared__ u16 Ps[128][68];

    const u16* qb = (const u16*)qkv;
    const size_t bb = (size_t)(b * NN);
    const float CE = 0.125f * 1.44269504f;   // softmax scale folded into exp2

    // Q fragments in registers: wave wv owns q-rows qp*128 + wv*16 + fr.
    short8 aq[2];
#pragma unroll
    for (int ks = 0; ks < 2; ks++)
        aq[ks] = *(const short8*)(qb + (bb + qp * 128 + wv * 16 + fr) * 768
                                  + h * 64 + ks * 32 + q8);

    f32x4 O[4];
    float m_i[4], l_i[4];
#pragma unroll
    for (int t = 0; t < 4; t++) {
        O[t] = (f32x4){0.f, 0.f, 0.f, 0.f};
        m_i[t] = -1e30f; l_i[t] = 0.f;
    }

    for (int c = 0; c < 4; c++) {
        __syncthreads();            // previous chunk's LDS reads complete
#pragma unroll
        for (int i = 0; i < 2; i++) {
            int idx = i * 512 + tid;
            int r = idx >> 3, seg = idx & 7;
            uint4 u = *((const uint4*)(qb + (bb + c * 128 + r) * 768 + 256 + h * 64) + seg);
            *(uint4*)&Ks[r][seg * 8] = u;
            uint4 v = *((const uint4*)(qb + (bb + c * 128 + r) * 768 + 512 + h * 64) + seg);
            // V^T store, 16B-granular XOR swizzle (seg == d>>3 for all 8 elems)
            u16* dst = &Vts[seg * 8][r ^ (seg << 3)];
            dst[0*136] = (u16)(v.x & 0xffff); dst[1*136] = (u16)(v.x >> 16);
            dst[2*136] = (u16)(v.y & 0xffff); dst[3*136] = (u16)(v.y >> 16);
            dst[4*136] = (u16)(v.z & 0xffff); dst[5*136] = (u16)(v.z >> 16);
            dst[6*136] = (u16)(v.w & 0xffff); dst[7*136] = (u16)(v.w >> 16);
        }
        __syncthreads();

        f32x4 S[8];
#pragma unroll
        for (int t = 0; t < 8; t++) S[t] = (f32x4){0.f, 0.f, 0.f, 0.f};
        __builtin_amdgcn_s_setprio(1);
#pragma unroll
        for (int ks = 0; ks < 2; ks++) {
#pragma unroll
            for (int t = 0; t < 8; t++) {
                short8 bk = *(const short8*)&Ks[t * 16 + fr][ks * 32 + q8];
                S[t] = __builtin_amdgcn_mfma_f32_16x16x32_bf16(aq[ks], bk, S[t], 0, 0, 0);
            }
        }
        __builtin_amdgcn_s_setprio(0);

        float mc[4];
#pragma unroll
        for (int r = 0; r < 4; r++) {
            float mm = -1e30f;
#pragma unroll
            for (int t = 0; t < 8; t++) mm = fmaxf(mm, S[t][r]);
            mc[r] = mm;
        }
#pragma unroll
        for (int msk = 1; msk < 16; msk <<= 1)
#pragma unroll
            for (int r = 0; r < 4; r++) mc[r] = fmaxf(mc[r], __shfl_xor(mc[r], msk));

        float alpha[4], ls[4];
#pragma unroll
        for (int r = 0; r < 4; r++) {
            float mn = fmaxf(m_i[r], mc[r]);
            alpha[r] = __builtin_amdgcn_exp2f((m_i[r] - mn) * CE);
            m_i[r] = mn;
            ls[r] = 0.f;
        }
        // rescale O before accumulating this chunk's PV
#pragma unroll
        for (int t = 0; t < 4; t++)
#pragma unroll
            for (int r = 0; r < 4; r++) O[t][r] *= alpha[r];

        // two 64-col halves: write P (wave-local), then PV on that half
#pragma unroll
        for (int hf = 0; hf < 2; hf++) {
#pragma unroll
            for (int tl = 0; tl < 4; tl++) {
                int t = hf * 4 + tl;
#pragma unroll
                for (int r = 0; r < 4; r++) {
                    float p = __builtin_amdgcn_exp2f((S[t][r] - m_i[r]) * CE);
                    Ps[wv * 16 + quad * 4 + r][tl * 16 + fr] = f2bu(p);
                    ls[r] += p;
                }
            }
            __builtin_amdgcn_s_setprio(1);
#pragma unroll
            for (int ks = 0; ks < 2; ks++) {
                short8 ap = *(const short8*)&Ps[wv * 16 + fr][ks * 32 + q8];
                int g = hf * 2 + ks;
#pragma unroll
                for (int t = 0; t < 4; t++) {
                    short8 bv = *(const short8*)&Vts[t * 16 + fr]
                                    [(g * 32 + q8) ^ ((t * 2 + (fr >> 3)) << 3)];
                    O[t] = __builtin_amdgcn_mfma_f32_16x16x32_bf16(ap, bv, O[t], 0, 0, 0);
                }
            }
            __builtin_amdgcn_s_setprio(0);
        }

#pragma unroll
        for (int msk = 1; msk < 16; msk <<= 1)
#pragma unroll
            for (int r = 0; r < 4; r++) ls[r] += __shfl_xor(ls[r], msk);
#pragma unroll
        for (int r = 0; r < 4; r++) l_i[r] = l_i[r] * alpha[r] + ls[r];
    }

#pragma unroll
    for (int t = 0; t < 4; t++)
#pragma unroll
        for (int r = 0; r < 4; r++) {
            int q = qp * 128 + wv * 16 + quad * 4 + r;
            out[(bb + q) * 256 + h * 64 + t * 16 + fr] = f2bu(O[t][r] / l_i[r]);
        }
}

// out = LN(X + Y); optional bf16 duplicate. One wave per row, zero barriers.
__global__ void add_ln_kernel(const float* __restrict__ X, const float* __restrict__ Y,
                              const float* __restrict__ g, const float* __restrict__ bt,
                              float* __restrict__ out, u16* __restrict__ dup)
{
    int wv = threadIdx.x >> 6, lane = threadIdx.x & 63;
    int row = blockIdx.x * 4 + wv;
    size_t base = (size_t)row * DD + lane * 4;
    f32x4 v = *(const f32x4*)&X[base] + *(const f32x4*)&Y[base];
    float s = v[0] + v[1] + v[2] + v[3];
#pragma unroll
    for (int m = 1; m < 64; m <<= 1) s += __shfl_xor(s, m);
    float mean = s * (1.f / DD);
    f32x4 d;
#pragma unroll
    for (int k = 0; k < 4; k++) d[k] = v[k] - mean;
    float q = d[0]*d[0] + d[1]*d[1] + d[2]*d[2] + d[3]*d[3];
#pragma unroll
    for (int m = 1; m < 64; m <<= 1) q += __shfl_xor(q, m);
    float inv = rsqrtf(q * (1.f / DD) + EPSF);
    f32x4 gv = *(const f32x4*)&g[lane * 4];
    f32x4 bv = *(const f32x4*)&bt[lane * 4];
    f32x4 o;
#pragma unroll
    for (int k = 0; k < 4; k++) o[k] = d[k] * inv * gv[k] + bv[k];
    *(f32x4*)&out[base] = o;
    if (dup) st4b(&dup[base], o);
}

// pool with BN2 fused: normalizes h2 inline (stats in sums/sumsq), then
// masked max + full-sum/L. Deletes the bn_apply pass over h2 (66MB traffic).
__global__ void pool_norm(const float* __restrict__ enc, const int* __restrict__ lengths,
                          const float* __restrict__ sums, const float* __restrict__ sumsq,
                          const float* __restrict__ g, const float* __restrict__ bt,
                          int R, float* __restrict__ poolbuf)
{
    int b = blockIdx.x;
    int wv = threadIdx.x >> 6, lane = threadIdx.x & 63;
    int L = lengths[b];
    if (L < 1) L = 1;
    float invR = 1.f / (float)R;
    f32x4 sm = *(const f32x4*)&sums[lane * 4];
    f32x4 sq = *(const f32x4*)&sumsq[lane * 4];
    f32x4 gv = *(const f32x4*)&g[lane * 4];
    f32x4 bv = *(const f32x4*)&bt[lane * 4];
    f32x4 mean, rsv;
#pragma unroll
    for (int k = 0; k < 4; k++) {
        mean[k] = sm[k] * invR;
        float var = sq[k] * invR - mean[k] * mean[k];
        rsv[k] = rsqrtf(fmaxf(var, 0.f) + EPSF) * gv[k];
    }
    f32x4 s  = (f32x4){0.f, 0.f, 0.f, 0.f};
    f32x4 mx = (f32x4){-1e30f, -1e30f, -1e30f, -1e30f};
    for (int n = wv; n < NN; n += 4) {
        f32x4 v = *(const f32x4*)&enc[((size_t)b * NN + n) * DD + lane * 4];
#pragma unroll
        for (int k = 0; k < 4; k++) v[k] = (v[k] - mean[k]) * rsv[k] + bv[k];
        s += v;
        if (n < L) {
#pragma unroll
            for (int k = 0; k < 4; k++) mx[k] = fmaxf(mx[k], v[k]);
        }
    }
    __shared__ f32x4 rs[4][64], rm[4][64];
    rs[wv][lane] = s; rm[wv][lane] = mx;
    __syncthreads();
    if (threadIdx.x < 64) {
        f32x4 ts = rs[0][lane], tm = rm[0][lane];
#pragma unroll
        for (int w = 1; w < 4; w++) {
            ts += rs[w][lane];
#pragma unroll
            for (int k = 0; k < 4; k++) tm[k] = fmaxf(tm[k], rm[w][lane][k]);
        }
        float invL = 1.f / (float)L;
#pragma unroll
        for (int k = 0; k < 4; k++) {
            poolbuf[b * 512 + lane * 4 + k]       = tm[k];
            poolbuf[b * 512 + 256 + lane * 4 + k] = ts[k] * invL;
        }
    }
}

__global__ void head_kernel(const float* __restrict__ poolbuf, const float* __restrict__ lin_w,
                            const float* __restrict__ lin_b, const float* __restrict__ g,
                            const float* __restrict__ bt, float* __restrict__ out)
{
    int b = threadIdx.x;
    float r0 = lin_b[0], r1 = lin_b[1];
    for (int k = 0; k < 512; k++) {
        float p = poolbuf[b * 512 + k];
        r0 += p * lin_w[k];
        r1 += p * lin_w[512 + k];
    }
    __shared__ float s0[64], s1[64], mstat[4];
    s0[b] = r0; s1[b] = r1; __syncthreads();
    if (b == 0) {
        float a0 = 0, a1 = 0, q0 = 0, q1 = 0;
        for (int i = 0; i < 64; i++) { a0 += s0[i]; a1 += s1[i]; }
        a0 *= (1.f / 64.f); a1 *= (1.f / 64.f);
        for (int i = 0; i < 64; i++) {
            float d0 = s0[i] - a0, d1 = s1[i] - a1;
            q0 += d0 * d0; q1 += d1 * d1;
        }
        mstat[0] = a0; mstat[1] = a1; mstat[2] = q0 * (1.f / 64.f); mstat[3] = q1 * (1.f / 64.f);
    }
    __syncthreads();
    float z0 = (r0 - mstat[0]) * rsqrtf(mstat[2] + EPSF) * g[0] + bt[0];
    float z1 = (r1 - mstat[1]) * rsqrtf(mstat[3] + EPSF) * g[1] + bt[1];
    float mx = fmaxf(z0, z1);
    float e0 = __expf(z0 - mx), e1 = __expf(z1 - mx);
    float inv = 1.f / (e0 + e1);
    out[b * 2 + 0] = e0 * inv;
    out[b * 2 + 1] = e1 * inv;
}

extern "C" void kernel_launch(void* const* d_in, const int* in_sizes, int n_in,
                              void* d_out, int out_size, void* d_ws, size_t ws_size,
                              hipStream_t stream)
{
    (void)in_sizes; (void)n_in; (void)out_size; (void)ws_size;
    const float* x          = (const float*)d_in[0];
    const float* edge_attr  = (const float*)d_in[1];
    const float* W1         = (const float*)d_in[5];
    const float* W2         = (const float*)d_in[6];
    const float* W3         = (const float*)d_in[7];
    const float* b3         = (const float*)d_in[8];
    const float* gcn_bias   = (const float*)d_in[9];
    const float* bn1_g      = (const float*)d_in[10];
    const float* bn1_b      = (const float*)d_in[11];
    const float* in_proj_w  = (const float*)d_in[12];
    const float* in_proj_b  = (const float*)d_in[13];
    const float* out_proj_w = (const float*)d_in[14];
    const float* out_proj_b = (const float*)d_in[15];
    const float* ln1_g      = (const float*)d_in[16];
    const float* ln1_b      = (const float*)d_in[17];
    const float* lin1_w     = (const float*)d_in[18];
    const float* lin1_b     = (const float*)d_in[19];
    const float* lin2_w     = (const float*)d_in[20];
    const float* lin2_b     = (const float*)d_in[21];
    const float* ln2_g      = (const float*)d_in[22];
    const float* ln2_b      = (const float*)d_in[23];
    const float* bn2_g      = (const float*)d_in[24];
    const float* bn2_b      = (const float*)d_in[25];
    const float* lin_w      = (const float*)d_in[26];
    const float* lin_b      = (const float*)d_in[27];
    const float* bn3_g      = (const float*)d_in[28];
    const float* bn3_b      = (const float*)d_in[29];

    // ---- Workspace layout (~187 MB) ----
    char* p = (char*)d_ws;
    u16*   big   = (u16*)p;   p += (size_t)BN_TOT * 1024 * 2;   // 64 MiB: [xb|(unused)|eaggb] -> qkv -> ffa
    float* bufA  = (float*)p; p += (size_t)BN_TOT * 256 * 4;    // aggM/h -> ffb
    float* bufB  = (float*)p; p += (size_t)BN_TOT * 256 * 4;    // y1 -> attnp -> h2
    float* bufC  = (float*)p; p += (size_t)BN_TOT * 256 * 4;    // agg1 -> h1
    u16*   bufP  = (u16*)p;   p += (size_t)BN_TOT * 256 * 2;    // 16.8 MB: hb -> attnoutb -> h1b
    float* deg   = (float*)p; p += (size_t)BN_TOT * 4;
    u16*   Mb    = (u16*)p;   p += 256 * 64 * 2;
    float* sb    = (float*)p; p += 1024;
    float* stats = (float*)p; p += 4 * 256 * 4;
    float* psum  = (float*)p; p += 512 * 256 * 4;               // bn partials
    float* psumsq= (float*)p; p += 512 * 256 * 4;
    float* poolbuf=(float*)p; p += 64 * 512 * 4;
    int*   flags = (int*)p;   p += 256;
    int*   erc   = (int*)p;   p += BE_TOT * 4;
    int*   ecc   = (int*)p;   p += BE_TOT * 4;
    int*   lenc  = (int*)p;   p += 256;
    uint2* edat  = (uint2*)p; p += (size_t)BE_TOT * 8;
    int*   noff  = (int*)p;   p += BN_TOT * 4;
    u16*   W13b  = (u16*)p;   p += 256 * 320 * 2;
    u16*   ipwb  = (u16*)p;   p += 768 * 256 * 2;
    u16*   opwb  = (u16*)p;   p += 256 * 256 * 2;
    u16*   l1wb  = (u16*)p;   p += 1024 * 256 * 2;
    u16*   l2wb  = (u16*)p;   p += 256 * 1024 * 2;

    // bf16 temporaries inside big (all dead before qkv is written at in_proj)
    u16* xb    = big;                              // 32768 x 320
    u16* eaggb = big + (size_t)BN_TOT * (320+256); // 32768 x 64
    bf16* qkv  = (bf16*)big;
    bf16* ffa  = (bf16*)big;

    float* y1      = bufB;
    float* agg1    = bufC;
    float* aggM    = bufA;    // becomes h in finalize
    float* h       = bufA;
    u16*   hb      = bufP;
    u16*   attnoutb= bufP;    // hb dead after in_proj GEMM
    float* attnp   = bufB;    // y1 dead after finalize
    float* h1      = bufC;    // agg1 dead after finalize
    u16*   h1b     = bufP;    // attnoutb dead after out_proj GEMM
    float* ffb     = bufA;    // h dead after add_ln #1
    float* h2      = bufB;    // attnp dead after add_ln #1

    hipMemsetAsync(stats, 0, 4 * 256 * 4, stream);

    detect_kernel<<<1, 1, 0, stream>>>((const int*)d_in[4], flags);
    conv_i2<<<(2 * BE_TOT + 255) / 256, 256, 0, stream>>>(d_in[2], erc, d_in[3], ecc,
                                                          BE_TOT, flags);
    conv_i<<<1, 64, 0, stream>>>(d_in[4], lenc, BB, flags);

    // input conversion + fused weight conversions
    conv_pad<<<(BN_TOT * 80 + 255) / 256, 256, 0, stream>>>(x, xb, BN_TOT, FINK, 320);
    conv_w4<<<768, 256, 0, stream>>>(in_proj_w, ipwb, out_proj_w, opwb,
                                     lin1_w, l1wb, lin2_w, l2wb);

    prep_W13<<<256, 320, 0, stream>>>(W3, W1, W13b);
    prep_M<<<256, 64, 0, stream>>>(W3, W2, Mb, sb);
    sort_edges<<<BB, 512, 0, stream>>>(ecc, erc, deg, noff, edat);

    // y1 = x @ (W3a@W1).T + b3  (xs GEMM folded into the weight)
    gemm_bf<float, 0><<<dim3(2, 256), 256, 0, stream>>>(
        xb, W13b, b3, y1, BN_TOT, 256, 320, 320, 320);

    edge_gather<<<BN_TOT, 256, 0, stream>>>(edat, noff, y1, edge_attr, agg1, eaggb);
    gemm_bf<float, 0><<<dim3(2, 256), 256, 0, stream>>>(
        eaggb, Mb, nullptr, aggM, BN_TOT, 256, 64, 64, 64);

    gcn_finalize<<<BN_TOT / 4, 256, 0, stream>>>(agg1, aggM, y1, sb, deg, gcn_bias, lenc);

    bn_stats<<<512, 256, 0, stream>>>(h, psum, psumsq, BN_TOT);
    bn_reduce<<<32, 256, 0, stream>>>(psum, psumsq, stats, stats + 256);
    bn_apply<<<BN_TOT / 4, 256, 0, stream>>>(h, stats, stats + 256, bn1_g, bn1_b, BN_TOT, hb);

    gemm_bf<bf16, 0><<<dim3(6, 256), 256, 0, stream>>>(
        hb, ipwb, in_proj_b, qkv, BN_TOT, 768, 256, 256, 256);

    attn_mfma<<<BB * 4 * 4, 512, 0, stream>>>(qkv, attnoutb);

    gemm_bf<float, 0><<<dim3(2, 256), 256, 0, stream>>>(
        attnoutb, opwb, out_proj_b, attnp, BN_TOT, 256, 256, 256, 256);

    add_ln_kernel<<<BN_TOT / 4, 256, 0, stream>>>(h, attnp, ln1_g, ln1_b, h1, h1b);

    gemm_bf<bf16, 1><<<dim3(8, 256), 256, 0, stream>>>(
        h1b, l1wb, lin1_b, ffa, BN_TOT, 1024, 256, 256, 256);
    gemm_bf<float, 0><<<dim3(2, 256), 256, 0, stream>>>(
        (const u16*)ffa, l2wb, lin2_b, ffb, BN_TOT, 256, 1024, 1024, 1024);

    add_ln_kernel<<<BN_TOT / 4, 256, 0, stream>>>(h1, ffb, ln2_g, ln2_b, h2, nullptr);

    bn_stats<<<512, 256, 0, stream>>>(h2, psum, psumsq, BN_TOT);
    bn_reduce<<<32, 256, 0, stream>>>(psum, psumsq, stats + 512, stats + 768);

    pool_norm<<<64, 256, 0, stream>>>(h2, lenc, stats + 512, stats + 768,
                                      bn2_g, bn2_b, BN_TOT, poolbuf);
    head_kernel<<<1, 64, 0, stream>>>(poolbuf, lin_w, lin_b, bn3_g, bn3_b, (float*)d_out);
}

// Round 13
// 557.644 us; speedup vs baseline: 1.2536x; 1.0313x over previous
//
#include <hip/hip_runtime.h>
#include <hip/hip_bf16.h>

// Shapes
#define BB   64
#define NN   512
#define EE   2048
#define FINK 300
#define DD   256
#define BN_TOT (BB*NN)    // 32768
#define BE_TOT (BB*EE)    // 131072
#define EPSF 1e-5f

using bf16 = __hip_bfloat16;
typedef unsigned short u16;
typedef __attribute__((ext_vector_type(8))) short short8;
typedef __attribute__((ext_vector_type(4))) float f32x4;
typedef __attribute__((ext_vector_type(4))) unsigned short u16x4;

__device__ __forceinline__ float tf(float x) { return x; }
__device__ __forceinline__ float tf(bf16 x)  { return __bfloat162float(x); }
__device__ __forceinline__ void  stv(float* p, float v) { *p = v; }
__device__ __forceinline__ void  stv(bf16*  p, float v) { *p = __float2bfloat16(v); }

__device__ __forceinline__ u16 f2bu(float f) {
    bf16 b = __float2bfloat16(f);
    return *(u16*)&b;
}
// f32x4 -> 4x bf16 stored as one 8B write
__device__ __forceinline__ void st4b(u16* p, f32x4 v)
{
    u16x4 o;
    o[0] = f2bu(v[0]); o[1] = f2bu(v[1]); o[2] = f2bu(v[2]); o[3] = f2bu(v[3]);
    *(u16x4*)p = o;
}

// Direct global->LDS DMA, 16B per lane. LDS dst = wave-uniform base + lane*16.
__device__ __forceinline__ void gload16(const void* g, void* l)
{
    __builtin_amdgcn_global_load_lds((const __attribute__((address_space(1))) void*)g,
                                     (__attribute__((address_space(3))) void*)l, 16, 0, 0);
}

// Int dtype probe + lengths conversion fused. lengths[1] as int32 is in
// [256,512] iff int32 storage; it is the zero hi-word of lengths[0] iff int64.
__global__ void detect_kernel(const int* __restrict__ lengths, int* __restrict__ flags,
                              int* __restrict__ lenc)
{
    int wide = (lengths[1] == 0) ? 1 : 0;
    if (threadIdx.x == 0) flags[1] = wide;
    if (threadIdx.x < BB) lenc[threadIdx.x] = lengths[wide ? (threadIdx.x << 1) : threadIdx.x];
}

// both edge-index conversions in one launch
__global__ void conv_i2(const void* __restrict__ src1, int* __restrict__ dst1,
                        const void* __restrict__ src2, int* __restrict__ dst2,
                        int n, const int* __restrict__ flags)
{
    int i = blockIdx.x * 256 + threadIdx.x;
    int wide = flags[1];
    if (i < n) {
        dst1[i] = ((const int*)src1)[wide ? (i << 1) : i];
    } else if (i < 2 * n) {
        int k = i - n;
        dst2[k] = ((const int*)src2)[wide ? (k << 1) : k];
    }
}

// f32 (rows x sk) -> bf16 (rows x dk) zero-padded, 4 cols/thread.
__global__ void conv_pad(const float* __restrict__ src, u16* __restrict__ dst, int rows,
                         int sk, int dk)
{
    int dk4 = dk >> 2;
    int i = blockIdx.x * 256 + threadIdx.x;
    if (i >= rows * dk4) return;
    int r = i / dk4, c4 = (i - r * dk4) * 4;
    if (c4 < sk) {
        f32x4 v = *(const f32x4*)&src[(size_t)r * sk + c4];
        st4b(&dst[(size_t)r * dk + c4], v);
    } else {
        *(u16x4*)&dst[(size_t)r * dk + c4] = (u16x4){0, 0, 0, 0};
    }
}

// all four plain f32->bf16 weight conversions in one launch (quad ranges:
// ipw 49152, opw 16384, l1w 65536, l2w 65536 -> 196608 quads, 768 blocks)
__global__ void conv_w4(const float* __restrict__ s0, u16* __restrict__ d0,
                        const float* __restrict__ s1, u16* __restrict__ d1,
                        const float* __restrict__ s2, u16* __restrict__ d2,
                        const float* __restrict__ s3, u16* __restrict__ d3)
{
    int i = blockIdx.x * 256 + threadIdx.x;
    const float* s; u16* d; int off;
    if (i < 49152)       { s = s0; d = d0; off = i; }
    else if (i < 65536)  { s = s1; d = d1; off = i - 49152; }
    else if (i < 131072) { s = s2; d = d2; off = i - 65536; }
    else                 { s = s3; d = d3; off = i - 131072; }
    f32x4 v = *(const f32x4*)&s[(size_t)off * 4];
    st4b(&d[(size_t)off * 4], v);
}

// W13 = W3[:, :256] @ W1  (256 x 320 bf16, zero-padded cols 300..319).
// Folds the xs = x@W1.T GEMM into y1 = x@W13.T (+b3).
__global__ void prep_W13(const float* __restrict__ W3, const float* __restrict__ W1,
                         u16* __restrict__ W13b)
{
    int d = blockIdx.x;      // 0..255
    int f = threadIdx.x;     // 0..319
    float s = 0.f;
    if (f < FINK) {
        for (int j = 0; j < 256; j++)
            s += W3[d * 512 + j] * W1[j * FINK + f];
    }
    W13b[d * 320 + f] = f2bu(s);
}

// ---------------------------------------------------------------------------
// MFMA GEMM v2: tile 128x128, 4 waves, K-step 64; T2 XOR-swizzle BOTH sides
// (pre-swizzled global source col, linear LDS dest, XOR'd fragment reads).
// M,N multiples of 128; K multiple of 64; lda/ldw elems, rows 16B-aligned.
// ---------------------------------------------------------------------------
template<typename TC, int RELU>
__global__ __launch_bounds__(256)
void gemm_bf(const u16* __restrict__ A, const u16* __restrict__ W,
             const float* __restrict__ bias, TC* __restrict__ C,
             int M, int N, int K, int lda, int ldw)
{
    __shared__ u16 As[128 * 64];
    __shared__ u16 Ws[128 * 64];

    const int m0 = blockIdx.y * 128;
    const int n0 = blockIdx.x * 128;
    const int tid  = threadIdx.x;
    const int lane = tid & 63;
    const int wv   = tid >> 6;
    const int fr   = lane & 15;
    const int q8   = (lane >> 4) * 8;
    const int mb   = (wv >> 1) * 64;
    const int nb   = (wv & 1) * 64;

    const int r8  = lane >> 3;                 // 0..7 (staging row in 8-row group)
    const int csw = 8 * ((lane & 7) ^ r8);     // swizzled source col within BK=64
    const int frx = (fr & 7) << 3;             // read-side XOR (same involution)

    f32x4 acc[4][4];
#pragma unroll
    for (int i = 0; i < 4; i++)
#pragma unroll
        for (int j = 0; j < 4; j++) acc[i][j] = (f32x4){0.f, 0.f, 0.f, 0.f};

    for (int k0 = 0; k0 < K; k0 += 64) {
        __syncthreads();
#pragma unroll
        for (int j = 0; j < 4; j++) {
            int rowA = m0 + wv * 32 + j * 8 + r8;
            int rowW = n0 + wv * 32 + j * 8 + r8;
            gload16(A + (size_t)rowA * lda + k0 + csw, &As[(wv * 32 + j * 8) * 64]);
            gload16(W + (size_t)rowW * ldw + k0 + csw, &Ws[(wv * 32 + j * 8) * 64]);
        }
        __syncthreads();

#pragma unroll
        for (int ks = 0; ks < 2; ks++) {
            int rc = (ks * 32 + q8) ^ frx;
            short8 af[4], bf[4];
#pragma unroll
            for (int i = 0; i < 4; i++) af[i] = *(const short8*)&As[(mb + i * 16 + fr) * 64 + rc];
#pragma unroll
            for (int j = 0; j < 4; j++) bf[j] = *(const short8*)&Ws[(nb + j * 16 + fr) * 64 + rc];
#pragma unroll
            for (int i = 0; i < 4; i++)
#pragma unroll
                for (int j = 0; j < 4; j++)
                    acc[i][j] = __builtin_amdgcn_mfma_f32_16x16x32_bf16(af[i], bf[j], acc[i][j], 0, 0, 0);
        }
    }

#pragma unroll
    for (int i = 0; i < 4; i++) {
#pragma unroll
        for (int j = 0; j < 4; j++) {
            int gn = n0 + nb + j * 16 + fr;
            float bv = bias ? bias[gn] : 0.f;
#pragma unroll
            for (int r = 0; r < 4; r++) {
                int gm = m0 + mb + i * 16 + (lane >> 4) * 4 + r;
                float v = acc[i][j][r] + bv;
                if (RELU) v = fmaxf(v, 0.f);
                stv(&C[(size_t)gm * N + gn], v);
            }
        }
    }
}

// M = W3b @ W2 (256 x 64) f32+bf16; sb[d] = row-sum of W3b.
__global__ void prep_M(const float* __restrict__ W3, const float* __restrict__ W2,
                       u16* __restrict__ Mb, float* __restrict__ sb)
{
    int d = blockIdx.x, a = threadIdx.x;
    float s = 0.f;
    for (int j = 0; j < 256; j++)
        s += W3[d * 512 + 256 + j] * W2[j * 64 + a];
    Mb[d * 64 + a] = f2bu(s);
    if (a == 0) {
        float t = 0.f;
        for (int j = 0; j < 256; j++) t += W3[d * 512 + 256 + j];
        sb[d] = t;
    }
}

// ---------------------------------------------------------------------------
// Per-batch counting sort of edges by column. One block per batch, 512 thr.
// Emits flattened per-slot records edat = {(e<<16)|row, norm}.
// ---------------------------------------------------------------------------
__global__ __launch_bounds__(512)
void sort_edges(const int* __restrict__ ecol, const int* __restrict__ erow,
                float* __restrict__ deg, int* __restrict__ node_off,
                uint2* __restrict__ edat)
{
    const int b = blockIdx.x;
    const int t = threadIdx.x;
    const int base = b * EE;
    __shared__ int cnt[512];
    __shared__ int tmp[512];
    __shared__ int off2[512];

    cnt[t] = 0;
    __syncthreads();
    for (int e = t; e < EE; e += 512) atomicAdd(&cnt[ecol[base + e]], 1);
    __syncthreads();

    int v = cnt[t];
    deg[b * NN + t] = (float)(v + 1);
    tmp[t] = v;
    __syncthreads();
    for (int s = 1; s < 512; s <<= 1) {
        int y = (t >= s) ? tmp[t - s] : 0;
        __syncthreads();
        tmp[t] += y;
        __syncthreads();
    }
    int excl = tmp[t] - v;
    node_off[b * NN + t] = excl;
    off2[t] = excl;
    __syncthreads();
    for (int e = t; e < EE; e += 512) {
        int c = ecol[base + e];
        int r = erow[base + e];
        int pos = atomicAdd(&off2[c], 1);
        float nrm = rsqrtf((float)((cnt[r] + 1) * (cnt[c] + 1)));
        edat[base + pos] = make_uint2(((unsigned)e << 16) | (unsigned)r,
                                      __float_as_uint(nrm));
    }
}

// ---------------------------------------------------------------------------
// Gather aggregation (no atomics, no pointer chase): one block per node.
// ---------------------------------------------------------------------------
__global__ __launch_bounds__(256)
void edge_gather(const uint2* __restrict__ edat, const int* __restrict__ node_off,
                 const float* __restrict__ y1, const float* __restrict__ eattr,
                 float* __restrict__ agg1, u16* __restrict__ eaggb)
{
    const int j = blockIdx.x;
    const int b = j >> 9;
    const int cc = j & 511;
    const int tid  = threadIdx.x;
    const int wv   = tid >> 6;
    const int lane = tid & 63;
    const int start = node_off[j];
    const int end   = (cc == 511) ? EE : node_off[j + 1];

    f32x4 acc = (f32x4){0.f, 0.f, 0.f, 0.f};
    float acce = 0.f;
    for (int i = start + wv; i < end; i += 4) {
        uint2 ed = edat[(size_t)b * EE + i];
        float nw = __uint_as_float(ed.y);
        int r = (int)(ed.x & 0xffffu);
        int e = (int)(ed.x >> 16);
        f32x4 yv = *(const f32x4*)&y1[((size_t)(b * NN + r)) * 256 + lane * 4];
        acc += nw * yv;
        acce += nw * eattr[((size_t)(b * EE + e)) * 64 + lane];
    }

    __shared__ f32x4 redA[4][64];
    __shared__ float redB[4][64];
    redA[wv][lane] = acc;
    redB[wv][lane] = acce;
    __syncthreads();
    if (tid < 64) {
        f32x4 s = redA[0][tid];
        float se = redB[0][tid];
#pragma unroll
        for (int w = 1; w < 4; w++) { s += redA[w][tid]; se += redB[w][tid]; }
        *(f32x4*)&agg1[(size_t)j * 256 + tid * 4] = s;
        eaggb[(size_t)j * 64 + tid] = f2bu(se);
    }
}

// gcn_finalize + BN1 partial-stats fused: h = tanh(...)*mask -> aggM, and
// per-block partial sum/sumsq of h accumulated inline (deletes bn_stats#1's
// full 33MB re-read). 512 blocks x 4 waves; wave handles full rows strided.
__global__ __launch_bounds__(256)
void gcn_fin_stats(const float* __restrict__ agg1, float* __restrict__ aggM,
                   const float* __restrict__ y1, const float* __restrict__ sb,
                   const float* __restrict__ deg, const float* __restrict__ gcn_bias,
                   const int* __restrict__ lengths,
                   float* __restrict__ psum, float* __restrict__ psumsq)
{
    int wv = threadIdx.x >> 6, lane = threadIdx.x & 63;
    int d4 = lane * 4;
    f32x4 sv = *(const f32x4*)&sb[d4];
    f32x4 gb = *(const f32x4*)&gcn_bias[d4];
    f32x4 s = (f32x4){0.f, 0.f, 0.f, 0.f};
    f32x4 q = (f32x4){0.f, 0.f, 0.f, 0.f};
    for (int j = blockIdx.x * 4 + wv; j < BN_TOT; j += 2048) {
        size_t base = (size_t)j * 256 + d4;
        float inv = 1.f / deg[j];
        f32x4 a1 = *(const f32x4*)&agg1[base];
        f32x4 aM = *(const f32x4*)&aggM[base];
        f32x4 yv = *(const f32x4*)&y1[base];
        int b = j >> 9, pp = j & 511;
        bool live = (pp < lengths[b]);
        f32x4 o;
#pragma unroll
        for (int k = 0; k < 4; k++) {
            float a = (a1[k] + aM[k] + (yv[k] + sv[k]) * inv) * inv;
            o[k] = live ? tanhf(a + gb[k]) : 0.f;
        }
        *(f32x4*)&aggM[base] = o;
        s += o; q += o * o;
    }
    __shared__ f32x4 rs[4][64], rq[4][64];
    rs[wv][lane] = s; rq[wv][lane] = q;
    __syncthreads();
    if (threadIdx.x < 64) {
        f32x4 ts = rs[0][lane], tq = rq[0][lane];
#pragma unroll
        for (int w = 1; w < 4; w++) { ts += rs[w][lane]; tq += rq[w][lane]; }
        *(f32x4*)&psum[blockIdx.x * DD + lane * 4]   = ts;
        *(f32x4*)&psumsq[blockIdx.x * DD + lane * 4] = tq;
    }
}

// fold 512 partial vectors -> sums/sumsq. 32 blocks; 16 atomics/address max.
__global__ void bn_reduce(const float* __restrict__ psum, const float* __restrict__ psumsq,
                          float* __restrict__ sums, float* __restrict__ sumsq)
{
    int arr = blockIdx.x & 1;
    int chunk = blockIdx.x >> 1;     // 0..15, 32 partials each
    int d = threadIdx.x;
    const float* src = arr ? psumsq : psum;
    float acc = 0.f;
    int i0 = chunk * 32;
    for (int i = i0; i < i0 + 32; i++) acc += src[i * DD + d];
    atomicAdd(arr ? &sumsq[d] : &sums[d], acc);
}

// X normalized in place; optional bf16 duplicate. f32x4 / 4 per thread.
__global__ void bn_apply(float* __restrict__ X, const float* __restrict__ sums,
                         const float* __restrict__ sumsq, const float* __restrict__ g,
                         const float* __restrict__ bt, int R, u16* __restrict__ dup)
{
    int idx4 = blockIdx.x * 256 + threadIdx.x;
    int d4 = (idx4 & 63) * 4;
    size_t base = (size_t)idx4 * 4;
    float invR = 1.f / (float)R;
    f32x4 sm = *(const f32x4*)&sums[d4];
    f32x4 sq = *(const f32x4*)&sumsq[d4];
    f32x4 gv = *(const f32x4*)&g[d4];
    f32x4 bv = *(const f32x4*)&bt[d4];
    f32x4 x  = *(const f32x4*)&X[base];
    f32x4 o;
#pragma unroll
    for (int k = 0; k < 4; k++) {
        float m   = sm[k] * invR;
        float var = sq[k] * invR - m * m;
        o[k] = (x[k] - m) * rsqrtf(fmaxf(var, 0.f) + EPSF) * gv[k] + bv[k];
    }
    *(f32x4*)&X[base] = o;
    if (dup) st4b(&dup[base], o);
}

// ---------------------------------------------------------------------------
// MFMA flash attention. v6: 512-thread blocks, 8 waves, 128 q-rows per
// block; grid 1024, qp = bid>>8 XCD-coherent. Ps is WAVE-LOCAL, PV in two
// 64-col halves over [128][68] Ps: LDS 52 KB.
// ---------------------------------------------------------------------------
__global__ __launch_bounds__(512, 2)
void attn_mfma(const bf16* __restrict__ qkv, u16* __restrict__ out)
{
    const int bid = blockIdx.x;
    const int qp = bid >> 8;        // 0..3 (slow bits -> XCD-coherent (b,h))
    const int pr = bid & 255;
    const int h  = pr & 3;
    const int b  = pr >> 2;

    const int tid  = threadIdx.x;
    const int lane = tid & 63;
    const int wv   = tid >> 6;      // 0..7
    const int fr   = lane & 15;
    const int quad = lane >> 4;
    const int q8   = quad * 8;

    __shared__ u16 Ks[128][72];
    __shared__ u16 Vts[64][136];
    __shared__ u16 Ps[128][68];

    const u16* qb = (const u16*)qkv;
    const size_t bb = (size_t)(b * NN);
    const float CE = 0.125f * 1.44269504f;   // softmax scale folded into exp2

    // Q fragments in registers: wave wv owns q-rows qp*128 + wv*16 + fr.
    short8 aq[2];
#pragma unroll
    for (int ks = 0; ks < 2; ks++)
        aq[ks] = *(const short8*)(qb + (bb + qp * 128 + wv * 16 + fr) * 768
                                  + h * 64 + ks * 32 + q8);

    f32x4 O[4];
    float m_i[4], l_i[4];
#pragma unroll
    for (int t = 0; t < 4; t++) {
        O[t] = (f32x4){0.f, 0.f, 0.f, 0.f};
        m_i[t] = -1e30f; l_i[t] = 0.f;
    }

    for (int c = 0; c < 4; c++) {
        __syncthreads();            // previous chunk's LDS reads complete
#pragma unroll
        for (int i = 0; i < 2; i++) {
            int idx = i * 512 + tid;
            int r = idx >> 3, seg = idx & 7;
            uint4 u = *((const uint4*)(qb + (bb + c * 128 + r) * 768 + 256 + h * 64) + seg);
            *(uint4*)&Ks[r][seg * 8] = u;
            uint4 v = *((const uint4*)(qb + (bb + c * 128 + r) * 768 + 512 + h * 64) + seg);
            // V^T store, 16B-granular XOR swizzle (seg == d>>3 for all 8 elems)
            u16* dst = &Vts[seg * 8][r ^ (seg << 3)];
            dst[0*136] = (u16)(v.x & 0xffff); dst[1*136] = (u16)(v.x >> 16);
            dst[2*136] = (u16)(v.y & 0xffff); dst[3*136] = (u16)(v.y >> 16);
            dst[4*136] = (u16)(v.z & 0xffff); dst[5*136] = (u16)(v.z >> 16);
            dst[6*136] = (u16)(v.w & 0xffff); dst[7*136] = (u16)(v.w >> 16);
        }
        __syncthreads();

        f32x4 S[8];
#pragma unroll
        for (int t = 0; t < 8; t++) S[t] = (f32x4){0.f, 0.f, 0.f, 0.f};
        __builtin_amdgcn_s_setprio(1);
#pragma unroll
        for (int ks = 0; ks < 2; ks++) {
#pragma unroll
            for (int t = 0; t < 8; t++) {
                short8 bk = *(const short8*)&Ks[t * 16 + fr][ks * 32 + q8];
                S[t] = __builtin_amdgcn_mfma_f32_16x16x32_bf16(aq[ks], bk, S[t], 0, 0, 0);
            }
        }
        __builtin_amdgcn_s_setprio(0);

        float mc[4];
#pragma unroll
        for (int r = 0; r < 4; r++) {
            float mm = -1e30f;
#pragma unroll
            for (int t = 0; t < 8; t++) mm = fmaxf(mm, S[t][r]);
            mc[r] = mm;
        }
#pragma unroll
        for (int msk = 1; msk < 16; msk <<= 1)
#pragma unroll
            for (int r = 0; r < 4; r++) mc[r] = fmaxf(mc[r], __shfl_xor(mc[r], msk));

        float alpha[4], ls[4];
#pragma unroll
        for (int r = 0; r < 4; r++) {
            float mn = fmaxf(m_i[r], mc[r]);
            alpha[r] = __builtin_amdgcn_exp2f((m_i[r] - mn) * CE);
            m_i[r] = mn;
            ls[r] = 0.f;
        }
        // rescale O before accumulating this chunk's PV
#pragma unroll
        for (int t = 0; t < 4; t++)
#pragma unroll
            for (int r = 0; r < 4; r++) O[t][r] *= alpha[r];

        // two 64-col halves: write P (wave-local), then PV on that half
#pragma unroll
        for (int hf = 0; hf < 2; hf++) {
#pragma unroll
            for (int tl = 0; tl < 4; tl++) {
                int t = hf * 4 + tl;
#pragma unroll
                for (int r = 0; r < 4; r++) {
                    float p = __builtin_amdgcn_exp2f((S[t][r] - m_i[r]) * CE);
                    Ps[wv * 16 + quad * 4 + r][tl * 16 + fr] = f2bu(p);
                    ls[r] += p;
                }
            }
            __builtin_amdgcn_s_setprio(1);
#pragma unroll
            for (int ks = 0; ks < 2; ks++) {
                short8 ap = *(const short8*)&Ps[wv * 16 + fr][ks * 32 + q8];
                int g = hf * 2 + ks;
#pragma unroll
                for (int t = 0; t < 4; t++) {
                    short8 bv = *(const short8*)&Vts[t * 16 + fr]
                                    [(g * 32 + q8) ^ ((t * 2 + (fr >> 3)) << 3)];
                    O[t] = __builtin_amdgcn_mfma_f32_16x16x32_bf16(ap, bv, O[t], 0, 0, 0);
                }
            }
            __builtin_amdgcn_s_setprio(0);
        }

#pragma unroll
        for (int msk = 1; msk < 16; msk <<= 1)
#pragma unroll
            for (int r = 0; r < 4; r++) ls[r] += __shfl_xor(ls[r], msk);
#pragma unroll
        for (int r = 0; r < 4; r++) l_i[r] = l_i[r] * alpha[r] + ls[r];
    }

#pragma unroll
    for (int t = 0; t < 4; t++)
#pragma unroll
        for (int r = 0; r < 4; r++) {
            int q = qp * 128 + wv * 16 + quad * 4 + r;
            out[(bb + q) * 256 + h * 64 + t * 16 + fr] = f2bu(O[t][r] / l_i[r]);
        }
}

// out = LN(X + Y); optional bf16 duplicate. One wave per row, zero barriers.
__global__ void add_ln_kernel(const float* __restrict__ X, const float* __restrict__ Y,
                              const float* __restrict__ g, const float* __restrict__ bt,
                              float* __restrict__ out, u16* __restrict__ dup)
{
    int wv = threadIdx.x >> 6, lane = threadIdx.x & 63;
    int row = blockIdx.x * 4 + wv;
    size_t base = (size_t)row * DD + lane * 4;
    f32x4 v = *(const f32x4*)&X[base] + *(const f32x4*)&Y[base];
    float s = v[0] + v[1] + v[2] + v[3];
#pragma unroll
    for (int m = 1; m < 64; m <<= 1) s += __shfl_xor(s, m);
    float mean = s * (1.f / DD);
    f32x4 d;
#pragma unroll
    for (int k = 0; k < 4; k++) d[k] = v[k] - mean;
    float q = d[0]*d[0] + d[1]*d[1] + d[2]*d[2] + d[3]*d[3];
#pragma unroll
    for (int m = 1; m < 64; m <<= 1) q += __shfl_xor(q, m);
    float inv = rsqrtf(q * (1.f / DD) + EPSF);
    f32x4 gv = *(const f32x4*)&g[lane * 4];
    f32x4 bv = *(const f32x4*)&bt[lane * 4];
    f32x4 o;
#pragma unroll
    for (int k = 0; k < 4; k++) o[k] = d[k] * inv * gv[k] + bv[k];
    *(f32x4*)&out[base] = o;
    if (dup) st4b(&dup[base], o);
}

// add_ln #2 + BN2 partial-stats fused (deletes bn_stats#2's 33MB re-read).
// 512 blocks x 4 waves; wave handles full rows strided by 2048.
__global__ __launch_bounds__(256)
void add_ln_stats(const float* __restrict__ X, const float* __restrict__ Y,
                  const float* __restrict__ g, const float* __restrict__ bt,
                  float* __restrict__ out,
                  float* __restrict__ psum, float* __restrict__ psumsq)
{
    int wv = threadIdx.x >> 6, lane = threadIdx.x & 63;
    f32x4 gv = *(const f32x4*)&g[lane * 4];
    f32x4 bv = *(const f32x4*)&bt[lane * 4];
    f32x4 s = (f32x4){0.f, 0.f, 0.f, 0.f};
    f32x4 qacc = (f32x4){0.f, 0.f, 0.f, 0.f};
    for (int row = blockIdx.x * 4 + wv; row < BN_TOT; row += 2048) {
        size_t base = (size_t)row * DD + lane * 4;
        f32x4 v = *(const f32x4*)&X[base] + *(const f32x4*)&Y[base];
        float sm = v[0] + v[1] + v[2] + v[3];
#pragma unroll
        for (int m = 1; m < 64; m <<= 1) sm += __shfl_xor(sm, m);
        float mean = sm * (1.f / DD);
        f32x4 d;
#pragma unroll
        for (int k = 0; k < 4; k++) d[k] = v[k] - mean;
        float qq = d[0]*d[0] + d[1]*d[1] + d[2]*d[2] + d[3]*d[3];
#pragma unroll
        for (int m = 1; m < 64; m <<= 1) qq += __shfl_xor(qq, m);
        float inv = rsqrtf(qq * (1.f / DD) + EPSF);
        f32x4 o;
#pragma unroll
        for (int k = 0; k < 4; k++) o[k] = d[k] * inv * gv[k] + bv[k];
        *(f32x4*)&out[base] = o;
        s += o; qacc += o * o;
    }
    __shared__ f32x4 rs[4][64], rq[4][64];
    rs[wv][lane] = s; rq[wv][lane] = qacc;
    __syncthreads();
    if (threadIdx.x < 64) {
        f32x4 ts = rs[0][lane], tq = rq[0][lane];
#pragma unroll
        for (int w = 1; w < 4; w++) { ts += rs[w][lane]; tq += rq[w][lane]; }
        *(f32x4*)&psum[blockIdx.x * DD + lane * 4]   = ts;
        *(f32x4*)&psumsq[blockIdx.x * DD + lane * 4] = tq;
    }
}

// pool with BN2 fused: normalizes h2 inline (stats in sums/sumsq), then
// masked max + full-sum/L.
__global__ void pool_norm(const float* __restrict__ enc, const int* __restrict__ lengths,
                          const float* __restrict__ sums, const float* __restrict__ sumsq,
                          const float* __restrict__ g, const float* __restrict__ bt,
                          int R, float* __restrict__ poolbuf)
{
    int b = blockIdx.x;
    int wv = threadIdx.x >> 6, lane = threadIdx.x & 63;
    int L = lengths[b];
    if (L < 1) L = 1;
    float invR = 1.f / (float)R;
    f32x4 sm = *(const f32x4*)&sums[lane * 4];
    f32x4 sq = *(const f32x4*)&sumsq[lane * 4];
    f32x4 gv = *(const f32x4*)&g[lane * 4];
    f32x4 bv = *(const f32x4*)&bt[lane * 4];
    f32x4 mean, rsv;
#pragma unroll
    for (int k = 0; k < 4; k++) {
        mean[k] = sm[k] * invR;
        float var = sq[k] * invR - mean[k] * mean[k];
        rsv[k] = rsqrtf(fmaxf(var, 0.f) + EPSF) * gv[k];
    }
    f32x4 s  = (f32x4){0.f, 0.f, 0.f, 0.f};
    f32x4 mx = (f32x4){-1e30f, -1e30f, -1e30f, -1e30f};
    for (int n = wv; n < NN; n += 4) {
        f32x4 v = *(const f32x4*)&enc[((size_t)b * NN + n) * DD + lane * 4];
#pragma unroll
        for (int k = 0; k < 4; k++) v[k] = (v[k] - mean[k]) * rsv[k] + bv[k];
        s += v;
        if (n < L) {
#pragma unroll
            for (int k = 0; k < 4; k++) mx[k] = fmaxf(mx[k], v[k]);
        }
    }
    __shared__ f32x4 rs[4][64], rm[4][64];
    rs[wv][lane] = s; rm[wv][lane] = mx;
    __syncthreads();
    if (threadIdx.x < 64) {
        f32x4 ts = rs[0][lane], tm = rm[0][lane];
#pragma unroll
        for (int w = 1; w < 4; w++) {
            ts += rs[w][lane];
#pragma unroll
            for (int k = 0; k < 4; k++) tm[k] = fmaxf(tm[k], rm[w][lane][k]);
        }
        float invL = 1.f / (float)L;
#pragma unroll
        for (int k = 0; k < 4; k++) {
            poolbuf[b * 512 + lane * 4 + k]       = tm[k];
            poolbuf[b * 512 + 256 + lane * 4 + k] = ts[k] * invL;
        }
    }
}

__global__ void head_kernel(const float* __restrict__ poolbuf, const float* __restrict__ lin_w,
                            const float* __restrict__ lin_b, const float* __restrict__ g,
                            const float* __restrict__ bt, float* __restrict__ out)
{
    int b = threadIdx.x;
    float r0 = lin_b[0], r1 = lin_b[1];
    for (int k = 0; k < 512; k++) {
        float p = poolbuf[b * 512 + k];
        r0 += p * lin_w[k];
        r1 += p * lin_w[512 + k];
    }
    __shared__ float s0[64], s1[64], mstat[4];
    s0[b] = r0; s1[b] = r1; __syncthreads();
    if (b == 0) {
        float a0 = 0, a1 = 0, q0 = 0, q1 = 0;
        for (int i = 0; i < 64; i++) { a0 += s0[i]; a1 += s1[i]; }
        a0 *= (1.f / 64.f); a1 *= (1.f / 64.f);
        for (int i = 0; i < 64; i++) {
            float d0 = s0[i] - a0, d1 = s1[i] - a1;
            q0 += d0 * d0; q1 += d1 * d1;
        }
        mstat[0] = a0; mstat[1] = a1; mstat[2] = q0 * (1.f / 64.f); mstat[3] = q1 * (1.f / 64.f);
    }
    __syncthreads();
    float z0 = (r0 - mstat[0]) * rsqrtf(mstat[2] + EPSF) * g[0] + bt[0];
    float z1 = (r1 - mstat[1]) * rsqrtf(mstat[3] + EPSF) * g[1] + bt[1];
    float mx = fmaxf(z0, z1);
    float e0 = __expf(z0 - mx), e1 = __expf(z1 - mx);
    float inv = 1.f / (e0 + e1);
    out[b * 2 + 0] = e0 * inv;
    out[b * 2 + 1] = e1 * inv;
}

extern "C" void kernel_launch(void* const* d_in, const int* in_sizes, int n_in,
                              void* d_out, int out_size, void* d_ws, size_t ws_size,
                              hipStream_t stream)
{
    (void)in_sizes; (void)n_in; (void)out_size; (void)ws_size;
    const float* x          = (const float*)d_in[0];
    const float* edge_attr  = (const float*)d_in[1];
    const float* W1         = (const float*)d_in[5];
    const float* W2         = (const float*)d_in[6];
    const float* W3         = (const float*)d_in[7];
    const float* b3         = (const float*)d_in[8];
    const float* gcn_bias   = (const float*)d_in[9];
    const float* bn1_g      = (const float*)d_in[10];
    const float* bn1_b      = (const float*)d_in[11];
    const float* in_proj_w  = (const float*)d_in[12];
    const float* in_proj_b  = (const float*)d_in[13];
    const float* out_proj_w = (const float*)d_in[14];
    const float* out_proj_b = (const float*)d_in[15];
    const float* ln1_g      = (const float*)d_in[16];
    const float* ln1_b      = (const float*)d_in[17];
    const float* lin1_w     = (const float*)d_in[18];
    const float* lin1_b     = (const float*)d_in[19];
    const float* lin2_w     = (const float*)d_in[20];
    const float* lin2_b     = (const float*)d_in[21];
    const float* ln2_g      = (const float*)d_in[22];
    const float* ln2_b      = (const float*)d_in[23];
    const float* bn2_g      = (const float*)d_in[24];
    const float* bn2_b      = (const float*)d_in[25];
    const float* lin_w      = (const float*)d_in[26];
    const float* lin_b      = (const float*)d_in[27];
    const float* bn3_g      = (const float*)d_in[28];
    const float* bn3_b      = (const float*)d_in[29];

    // ---- Workspace layout (~187 MB) ----
    char* p = (char*)d_ws;
    u16*   big   = (u16*)p;   p += (size_t)BN_TOT * 1024 * 2;   // 64 MiB: [xb|(unused)|eaggb] -> qkv -> ffa
    float* bufA  = (float*)p; p += (size_t)BN_TOT * 256 * 4;    // aggM/h -> ffb
    float* bufB  = (float*)p; p += (size_t)BN_TOT * 256 * 4;    // y1 -> attnp -> h2
    float* bufC  = (float*)p; p += (size_t)BN_TOT * 256 * 4;    // agg1 -> h1
    u16*   bufP  = (u16*)p;   p += (size_t)BN_TOT * 256 * 2;    // 16.8 MB: hb -> attnoutb -> h1b
    float* deg   = (float*)p; p += (size_t)BN_TOT * 4;
    u16*   Mb    = (u16*)p;   p += 256 * 64 * 2;
    float* sb    = (float*)p; p += 1024;
    float* stats = (float*)p; p += 4 * 256 * 4;
    float* psum  = (float*)p; p += 512 * 256 * 4;               // bn partials
    float* psumsq= (float*)p; p += 512 * 256 * 4;
    float* poolbuf=(float*)p; p += 64 * 512 * 4;
    int*   flags = (int*)p;   p += 256;
    int*   erc   = (int*)p;   p += BE_TOT * 4;
    int*   ecc   = (int*)p;   p += BE_TOT * 4;
    int*   lenc  = (int*)p;   p += 256;
    uint2* edat  = (uint2*)p; p += (size_t)BE_TOT * 8;
    int*   noff  = (int*)p;   p += BN_TOT * 4;
    u16*   W13b  = (u16*)p;   p += 256 * 320 * 2;
    u16*   ipwb  = (u16*)p;   p += 768 * 256 * 2;
    u16*   opwb  = (u16*)p;   p += 256 * 256 * 2;
    u16*   l1wb  = (u16*)p;   p += 1024 * 256 * 2;
    u16*   l2wb  = (u16*)p;   p += 256 * 1024 * 2;

    // bf16 temporaries inside big (all dead before qkv is written at in_proj)
    u16* xb    = big;                              // 32768 x 320
    u16* eaggb = big + (size_t)BN_TOT * (320+256); // 32768 x 64
    bf16* qkv  = (bf16*)big;
    bf16* ffa  = (bf16*)big;

    float* y1      = bufB;
    float* agg1    = bufC;
    float* aggM    = bufA;    // becomes h in finalize
    float* h       = bufA;
    u16*   hb      = bufP;
    u16*   attnoutb= bufP;    // hb dead after in_proj GEMM
    float* attnp   = bufB;    // y1 dead after finalize
    float* h1      = bufC;    // agg1 dead after finalize
    u16*   h1b     = bufP;    // attnoutb dead after out_proj GEMM
    float* ffb     = bufA;    // h dead after add_ln #1
    float* h2      = bufB;    // attnp dead after add_ln #1

    hipMemsetAsync(stats, 0, 4 * 256 * 4, stream);

    detect_kernel<<<1, 64, 0, stream>>>((const int*)d_in[4], flags, lenc);
    conv_i2<<<(2 * BE_TOT + 255) / 256, 256, 0, stream>>>(d_in[2], erc, d_in[3], ecc,
                                                          BE_TOT, flags);

    // input conversion + fused weight conversions
    conv_pad<<<(BN_TOT * 80 + 255) / 256, 256, 0, stream>>>(x, xb, BN_TOT, FINK, 320);
    conv_w4<<<768, 256, 0, stream>>>(in_proj_w, ipwb, out_proj_w, opwb,
                                     lin1_w, l1wb, lin2_w, l2wb);

    prep_W13<<<256, 320, 0, stream>>>(W3, W1, W13b);
    prep_M<<<256, 64, 0, stream>>>(W3, W2, Mb, sb);
    sort_edges<<<BB, 512, 0, stream>>>(ecc, erc, deg, noff, edat);

    // y1 = x @ (W3a@W1).T + b3  (xs GEMM folded into the weight)
    gemm_bf<float, 0><<<dim3(2, 256), 256, 0, stream>>>(
        xb, W13b, b3, y1, BN_TOT, 256, 320, 320, 320);

    edge_gather<<<BN_TOT, 256, 0, stream>>>(edat, noff, y1, edge_attr, agg1, eaggb);
    gemm_bf<float, 0><<<dim3(2, 256), 256, 0, stream>>>(
        eaggb, Mb, nullptr, aggM, BN_TOT, 256, 64, 64, 64);

    gcn_fin_stats<<<512, 256, 0, stream>>>(agg1, aggM, y1, sb, deg, gcn_bias, lenc,
                                           psum, psumsq);
    bn_reduce<<<32, 256, 0, stream>>>(psum, psumsq, stats, stats + 256);
    bn_apply<<<BN_TOT / 4, 256, 0, stream>>>(h, stats, stats + 256, bn1_g, bn1_b, BN_TOT, hb);

    gemm_bf<bf16, 0><<<dim3(6, 256), 256, 0, stream>>>(
        hb, ipwb, in_proj_b, qkv, BN_TOT, 768, 256, 256, 256);

    attn_mfma<<<BB * 4 * 4, 512, 0, stream>>>(qkv, attnoutb);

    gemm_bf<float, 0><<<dim3(2, 256), 256, 0, stream>>>(
        attnoutb, opwb, out_proj_b, attnp, BN_TOT, 256, 256, 256, 256);

    add_ln_kernel<<<BN_TOT / 4, 256, 0, stream>>>(h, attnp, ln1_g, ln1_b, h1, h1b);

    gemm_bf<bf16, 1><<<dim3(8, 256), 256, 0, stream>>>(
        h1b, l1wb, lin1_b, ffa, BN_TOT, 1024, 256, 256, 256);
    gemm_bf<float, 0><<<dim3(2, 256), 256, 0, stream>>>(
        (const u16*)ffa, l2wb, lin2_b, ffb, BN_TOT, 256, 1024, 1024, 1024);

    add_ln_stats<<<512, 256, 0, stream>>>(h1, ffb, ln2_g, ln2_b, h2, psum, psumsq);
    bn_reduce<<<32, 256, 0, stream>>>(psum, psumsq, stats + 512, stats + 768);

    pool_norm<<<64, 256, 0, stream>>>(h2, lenc, stats + 512, stats + 768,
                                      bn2_g, bn2_b, BN_TOT, poolbuf);
    head_kernel<<<1, 64, 0, stream>>>(poolbuf, lin_w, lin_b, bn3_g, bn3_b, (float*)d_out);
}